// Round 1
// baseline (1222.002 us; speedup 1.0000x reference)
//
#include <hip/hip_runtime.h>

#define DEVINL __device__ __forceinline__

static const int NPTS = 2048;

typedef __attribute__((ext_vector_type(8))) short bf16x8;
typedef __attribute__((ext_vector_type(4))) float f32x4;

DEVINL unsigned fenc(float x) {
    int b = __float_as_int(x);
    return (b < 0) ? ~(unsigned)b : ((unsigned)b | 0x80000000u);
}
DEVINL float fdec(unsigned u) {
    return (u & 0x80000000u) ? __int_as_float((int)(u & 0x7fffffffu))
                             : __int_as_float((int)~u);
}
DEVINL unsigned long long u64min(unsigned long long a, unsigned long long b) {
    return (b < a) ? b : a;
}
DEVINL unsigned short f2bf(float x) {  // round-to-nearest-even bf16 (finite inputs)
    unsigned u = __float_as_uint(x);
    return (unsigned short)((u + 0x7fffu + ((u >> 16) & 1u)) >> 16);
}
DEVINL float bf2f(unsigned short h) { return __uint_as_float(((unsigned)h) << 16); }

// ---------------------------------------------------------------------------
// Exact top-20 of a row held as v[32] per lane (col(j) = lane*4+(j&3)+(j>>2)*256).
// tau = 20th smallest of the 64 lane-minima; ballot-compact <=tau (E~25) ->
// u64 bitonic sort -> lanes 0..19. Fallback to 20x tournament when >64 cands.
// ---------------------------------------------------------------------------
DEVINL void topk20(float v[32], unsigned long long* cand, int lane,
                   int* __restrict__ Iout, int outBase) {
    float t16[16];
#pragma unroll
    for (int i = 0; i < 16; ++i) t16[i] = fminf(v[i], v[i + 16]);
#pragma unroll
    for (int i = 0; i < 8; ++i) t16[i] = fminf(t16[i], t16[i + 8]);
#pragma unroll
    for (int i = 0; i < 4; ++i) t16[i] = fminf(t16[i], t16[i + 4]);
    float s = fminf(fminf(t16[0], t16[1]), fminf(t16[2], t16[3]));
#pragma unroll
    for (int k = 2; k <= 64; k <<= 1) {
#pragma unroll
        for (int j = k >> 1; j >= 1; j >>= 1) {
            float o = __shfl_xor(s, j);
            bool keepmin = (((lane & j) == 0) == ((lane & k) == 0));
            s = keepmin ? fminf(s, o) : fmaxf(s, o);
        }
    }
    const float tau = __shfl(s, 19);
    int cnt = 0;
#pragma unroll
    for (int j = 0; j < 32; ++j) {
        bool pass = (v[j] <= tau);
        unsigned long long mask = __ballot(pass);
        if (pass) {
            int pos = cnt + (int)__popcll(mask & ((1ull << lane) - 1ull));
            if (pos < 64) {
                int col = lane * 4 + (j & 3) + ((j >> 2) << 8);
                cand[pos] = ((unsigned long long)fenc(v[j]) << 32) | (unsigned)col;
            }
        }
        cnt += (int)__popcll(mask);
    }
    if (cnt <= 64) {
        unsigned long long key = (lane < cnt) ? cand[lane] : ~0ull;
#pragma unroll
        for (int k = 2; k <= 64; k <<= 1) {
#pragma unroll
            for (int j = k >> 1; j >= 1; j >>= 1) {
                unsigned long long o = __shfl_xor(key, j);
                bool keepmin = (((lane & j) == 0) == ((lane & k) == 0));
                unsigned long long mn = u64min(key, o);
                unsigned long long mx = (key ^ o) ^ mn;
                key = keepmin ? mn : mx;
            }
        }
        if (lane < 20) Iout[outBase + lane] = (int)(unsigned)(key & 0xffffffffu);
    } else {
        unsigned long long vk[32];
#pragma unroll
        for (int j = 0; j < 32; ++j) {
            int col = lane * 4 + (j & 3) + ((j >> 2) << 8);
            vk[j] = ((unsigned long long)fenc(v[j]) << 32) | (unsigned)col;
        }
        unsigned long long last = 0ull;
        for (int it = 0; it < 20; ++it) {
            unsigned long long q16[16];
#pragma unroll
            for (int i = 0; i < 16; ++i) {
                unsigned long long a = (vk[i] > last) ? vk[i] : ~0ull;
                unsigned long long c = (vk[i + 16] > last) ? vk[i + 16] : ~0ull;
                q16[i] = u64min(a, c);
            }
#pragma unroll
            for (int i = 0; i < 8; ++i) q16[i] = u64min(q16[i], q16[i + 8]);
#pragma unroll
            for (int i = 0; i < 4; ++i) q16[i] = u64min(q16[i], q16[i + 4]);
            unsigned long long best = u64min(u64min(q16[0], q16[1]), u64min(q16[2], q16[3]));
#pragma unroll
            for (int off = 32; off >= 1; off >>= 1) {
                unsigned long long o = __shfl_down(best, off);
                best = u64min(best, o);
            }
            best = __shfl(best, 0);
            if (lane == 0) Iout[outBase + it] = (int)(unsigned)(best & 0xffffffffu);
            last = best;
        }
    }
}

// ---------------------------------------------------------------------------
// Fused KNN (C=64) with inline sq: block owns 8 rows; GEMM 8x2048x64 with A in
// LDS, B streamed (L2-resident); sq[m] accumulated per-thread alongside (same
// ascending-c order as before -> bit-identical distances).
// Occupancy restructure: Dr halved to [4][2048] (32 KB) and the epilogue/topk
// runs in two passes of 4 rows (wave w takes row w, then row 4+w). LDS drops
// 68->36 KB => 4 blocks/CU (16 waves/CU) instead of 2, hiding the topk's
// serial shfl chains under other blocks' GEMM issue. Bit-identical output.
// ---------------------------------------------------------------------------
__global__ __launch_bounds__(256, 4) void knnfused_kernel(const float* __restrict__ X, int bs,
                                                          int* __restrict__ Iout) {
    __shared__ float Dr[4 * NPTS];                // 32 KB
    __shared__ float As[64 * 8];                  //  2 KB
    __shared__ unsigned long long cand[4 * 64];   //  2 KB
    const int N = NPTS, K = 20;
    const int b = blockIdx.y, n0 = blockIdx.x * 8;
    const float* __restrict__ Xb = X + (size_t)b * bs;
    const int tid = threadIdx.x;
    if (tid < 128) {
        int c = tid >> 1, r4 = (tid & 1) * 4;
        *(float4*)&As[c * 8 + r4] = *(const float4*)&Xb[(size_t)c * N + n0 + r4];
    }
    __syncthreads();
    const int m0 = tid * 4, m1 = 1024 + tid * 4;
    float acc0[8][4], acc1[8][4], sq0[4], sq1[4];
#pragma unroll
    for (int r = 0; r < 8; ++r)
#pragma unroll
        for (int j = 0; j < 4; ++j) { acc0[r][j] = 0.f; acc1[r][j] = 0.f; }
#pragma unroll
    for (int j = 0; j < 4; ++j) { sq0[j] = 0.f; sq1[j] = 0.f; }
#pragma unroll 4
    for (int c = 0; c < 64; ++c) {
        float4 b0 = *(const float4*)&Xb[(size_t)c * N + m0];
        float4 b1 = *(const float4*)&Xb[(size_t)c * N + m1];
        float4 a0 = *(const float4*)&As[c * 8];
        float4 a1 = *(const float4*)&As[c * 8 + 4];
        sq0[0] += b0.x * b0.x; sq0[1] += b0.y * b0.y;
        sq0[2] += b0.z * b0.z; sq0[3] += b0.w * b0.w;
        sq1[0] += b1.x * b1.x; sq1[1] += b1.y * b1.y;
        sq1[2] += b1.z * b1.z; sq1[3] += b1.w * b1.w;
        float av[8] = {a0.x, a0.y, a0.z, a0.w, a1.x, a1.y, a1.z, a1.w};
#pragma unroll
        for (int r = 0; r < 8; ++r) {
            acc0[r][0] += av[r] * b0.x; acc0[r][1] += av[r] * b0.y;
            acc0[r][2] += av[r] * b0.z; acc0[r][3] += av[r] * b0.w;
            acc1[r][0] += av[r] * b1.x; acc1[r][1] += av[r] * b1.y;
            acc1[r][2] += av[r] * b1.z; acc1[r][3] += av[r] * b1.w;
        }
    }
    const float INF = __builtin_inff();
    // ---- pass 1: rows 0..3 -> Dr ----
#pragma unroll
    for (int r = 0; r < 4; ++r) {
        const int n = n0 + r;
        float d0[4] = {sq0[0] - 2.f * acc0[r][0], sq0[1] - 2.f * acc0[r][1],
                       sq0[2] - 2.f * acc0[r][2], sq0[3] - 2.f * acc0[r][3]};
        float d1[4] = {sq1[0] - 2.f * acc1[r][0], sq1[1] - 2.f * acc1[r][1],
                       sq1[2] - 2.f * acc1[r][2], sq1[3] - 2.f * acc1[r][3]};
#pragma unroll
        for (int j = 0; j < 4; ++j) {
            if (m0 + j == n) d0[j] = INF;
            if (m1 + j == n) d1[j] = INF;
        }
        *(float4*)&Dr[r * N + m0] = make_float4(d0[0], d0[1], d0[2], d0[3]);
        *(float4*)&Dr[r * N + m1] = make_float4(d1[0], d1[1], d1[2], d1[3]);
    }
    __syncthreads();
    const int w = tid >> 6, lane = tid & 63;
    float v[32];
#pragma unroll
    for (int q = 0; q < 8; ++q) {
        float4 x4 = *(const float4*)&Dr[w * N + lane * 4 + q * 256];
        v[q * 4 + 0] = x4.x; v[q * 4 + 1] = x4.y;
        v[q * 4 + 2] = x4.z; v[q * 4 + 3] = x4.w;
    }
    __syncthreads();  // all reads of Dr rows 0..3 done
    // ---- pass 2 stores: rows 4..7 -> Dr (overlaps with topk of pass 1) ----
#pragma unroll
    for (int r = 4; r < 8; ++r) {
        const int n = n0 + r;
        float d0[4] = {sq0[0] - 2.f * acc0[r][0], sq0[1] - 2.f * acc0[r][1],
                       sq0[2] - 2.f * acc0[r][2], sq0[3] - 2.f * acc0[r][3]};
        float d1[4] = {sq1[0] - 2.f * acc1[r][0], sq1[1] - 2.f * acc1[r][1],
                       sq1[2] - 2.f * acc1[r][2], sq1[3] - 2.f * acc1[r][3]};
#pragma unroll
        for (int j = 0; j < 4; ++j) {
            if (m0 + j == n) d0[j] = INF;
            if (m1 + j == n) d1[j] = INF;
        }
        *(float4*)&Dr[(r - 4) * N + m0] = make_float4(d0[0], d0[1], d0[2], d0[3]);
        *(float4*)&Dr[(r - 4) * N + m1] = make_float4(d1[0], d1[1], d1[2], d1[3]);
    }
    topk20(v, cand + w * 64, lane, Iout, (b * N + n0 + w) * K);
    __syncthreads();  // row 4..7 stores complete
#pragma unroll
    for (int q = 0; q < 8; ++q) {
        float4 x4 = *(const float4*)&Dr[w * N + lane * 4 + q * 256];
        v[q * 4 + 0] = x4.x; v[q * 4 + 1] = x4.y;
        v[q * 4 + 2] = x4.z; v[q * 4 + 3] = x4.w;
    }
    topk20(v, cand + w * 64, lane, Iout, (b * N + n0 + 4 + w) * K);
}

// ---------------------------------------------------------------------------
// select0: layer-0 (C=3) — scores inline, register topk.
// ---------------------------------------------------------------------------
__global__ __launch_bounds__(256) void select0_kernel(const float* __restrict__ X,
                                                      int* __restrict__ Iout) {
    const int N = NPTS, K = 20;
    __shared__ unsigned long long cand[4][64];
    const int w = threadIdx.x >> 6, lane = threadIdx.x & 63;
    const int rowg = blockIdx.x * 4 + w;
    const int b = rowg >> 11, n = rowg & 2047;
    const float* __restrict__ Xb = X + (size_t)b * 3 * N;
    const float xr = Xb[n], yr = Xb[N + n], zr = Xb[2 * N + n];
    const float INF = __builtin_inff();
    float v[32];
#pragma unroll
    for (int q = 0; q < 8; ++q) {
        const int base = lane * 4 + q * 256;
        const float4 xm = *(const float4*)&Xb[base];
        const float4 ym = *(const float4*)&Xb[N + base];
        const float4 zm = *(const float4*)&Xb[2 * N + base];
        float mx[4] = {xm.x, xm.y, xm.z, xm.w};
        float my[4] = {ym.x, ym.y, ym.z, ym.w};
        float mz[4] = {zm.x, zm.y, zm.z, zm.w};
#pragma unroll
        for (int j = 0; j < 4; ++j) {
            float sq = mx[j] * mx[j] + my[j] * my[j] + mz[j] * mz[j];
            float dot = xr * mx[j] + yr * my[j] + zr * mz[j];
            float d = sq - 2.f * dot;
            v[q * 4 + j] = (base + j == n) ? INF : d;
        }
    }
    topk20(v, &cand[w][0], lane, Iout, (b * N + n) * K);
}

// ---------------------------------------------------------------------------
// U/T GEMMs (unchanged).
// ---------------------------------------------------------------------------
template<int F, int C>
__global__ __launch_bounds__(256) void ut_kernel(const float* __restrict__ X, int bs,
                                                 const float* __restrict__ W,
                                                 const float* __restrict__ bias,
                                                 float* __restrict__ U, float* __restrict__ T) {
    const int N = NPTS;
    __shared__ float Ws2[64][C + 1];
    __shared__ float Wsd[64][C + 1];
    const int n0 = blockIdx.x * 64, f0 = blockIdx.y * 64, b = blockIdx.z;
    const int tid = threadIdx.x;
    for (int i = tid; i < 64 * C; i += 256) {
        int ff = i / C, c = i - ff * C;
        float w1 = W[(f0 + ff) * (2 * C) + c];
        float w2 = W[(f0 + ff) * (2 * C) + C + c];
        Ws2[ff][c] = w2;
        Wsd[ff][c] = w1 - w2;
    }
    __syncthreads();
    const int nt = tid & 15, fg = tid >> 4;
    const float* __restrict__ Xb = X + (size_t)b * bs;
    float au[4][4], av[4][4];
#pragma unroll
    for (int i = 0; i < 4; ++i)
#pragma unroll
        for (int j = 0; j < 4; ++j) { au[i][j] = 0.f; av[i][j] = 0.f; }
#pragma unroll 4
    for (int c = 0; c < C; ++c) {
        const float4 xv = *(const float4*)&Xb[(size_t)c * N + n0 + nt * 4];
#pragma unroll
        for (int fi = 0; fi < 4; ++fi) {
            float w2v = Ws2[fg * 4 + fi][c];
            float wdv = Wsd[fg * 4 + fi][c];
            au[fi][0] += w2v * xv.x; au[fi][1] += w2v * xv.y;
            au[fi][2] += w2v * xv.z; au[fi][3] += w2v * xv.w;
            av[fi][0] += wdv * xv.x; av[fi][1] += wdv * xv.y;
            av[fi][2] += wdv * xv.z; av[fi][3] += wdv * xv.w;
        }
    }
#pragma unroll
    for (int ni = 0; ni < 4; ++ni) {
        int n = n0 + nt * 4 + ni;
        float4 uv = make_float4(au[0][ni], au[1][ni], au[2][ni], au[3][ni]);
        *(float4*)&U[((size_t)b * N + n) * F + f0 + fg * 4] = uv;
    }
#pragma unroll
    for (int fi = 0; fi < 4; ++fi) {
        int f = f0 + fg * 4 + fi;
        float bv = bias[f];
        float4 tv = make_float4(av[fi][0] + bv, av[fi][1] + bv, av[fi][2] + bv, av[fi][3] + bv);
        *(float4*)&T[((size_t)b * F + f) * N + n0 + nt * 4] = tv;
    }
}

// ---------------------------------------------------------------------------
// Gather-max: block = 32 points x 8 f-groups. Writes fp32 Hc slice (optional,
// needed as next-layer KNN input) AND bf16 hi/lo into Ht[b][n][320] at column
// offset `hoff` (c-contiguous — the MFMA A-operand layout for conv0).
// ---------------------------------------------------------------------------
template<int F, bool WRITE_F32>
__global__ __launch_bounds__(256) void gathermax_kernel(const float* __restrict__ U,
                                                        const float* __restrict__ T,
                                                        const int* __restrict__ idx,
                                                        float* __restrict__ Y, int bsY,
                                                        unsigned short* __restrict__ HtH,
                                                        unsigned short* __restrict__ HtL,
                                                        int hoff) {
    const int N = NPTS, K = 20, FG = F / 8;
    __shared__ int sidx[32 * 20];
    const int b = blockIdx.y, n0 = blockIdx.x * 32, tid = threadIdx.x;
    const int p = tid >> 3, fg = tid & 7;
    for (int t = tid; t < 32 * K; t += 256) sidx[t] = idx[(b * N + n0) * K + t];
    __syncthreads();
    const int n = n0 + p;
    const float* __restrict__ Ub = U + (size_t)b * N * F;
    const int fbase = fg * FG;
    float mx[FG];
#pragma unroll
    for (int i = 0; i < FG; ++i) mx[i] = -__builtin_inff();
#pragma unroll 4
    for (int j = 0; j < K; ++j) {
        const int r = sidx[p * K + j];
        const float4* up = (const float4*)&Ub[(size_t)r * F + fbase];
#pragma unroll
        for (int q = 0; q < FG / 4; ++q) {
            float4 a = up[q];
            mx[q * 4 + 0] = fmaxf(mx[q * 4 + 0], a.x);
            mx[q * 4 + 1] = fmaxf(mx[q * 4 + 1], a.y);
            mx[q * 4 + 2] = fmaxf(mx[q * 4 + 2], a.z);
            mx[q * 4 + 3] = fmaxf(mx[q * 4 + 3], a.w);
        }
    }
    float val[FG];
#pragma unroll
    for (int i = 0; i < FG; ++i) {
        const int f = fbase + i;
        val[i] = T[((size_t)b * F + f) * N + n] + mx[i];
        if (WRITE_F32) Y[(size_t)b * bsY + (size_t)f * N + n] = val[i];
    }
    // bf16 hi/lo split, c-contiguous at Ht[b][n][hoff + fbase ...]
    unsigned short hs[FG], ls[FG];
#pragma unroll
    for (int i = 0; i < FG; ++i) {
        unsigned short h = f2bf(val[i]);
        hs[i] = h;
        ls[i] = f2bf(val[i] - bf2f(h));
    }
    const size_t hb = ((size_t)b * N + n) * 320 + hoff + fbase;
#pragma unroll
    for (int q = 0; q < FG / 8; ++q) {
        *(int4*)&HtH[hb + q * 8] = *(const int4*)&hs[q * 8];
        *(int4*)&HtL[hb + q * 8] = *(const int4*)&ls[q * 8];
    }
}

// ---------------------------------------------------------------------------
// conv0_w -> bf16 hi/lo split (one-shot, 1024x320 elements).
// ---------------------------------------------------------------------------
__global__ __launch_bounds__(256) void wsplit_kernel(const float* __restrict__ W,
                                                     unsigned short* __restrict__ WH,
                                                     unsigned short* __restrict__ WL) {
    const int e = blockIdx.x * 256 + threadIdx.x;
    float w = W[e];
    unsigned short h = f2bf(w);
    WH[e] = h;
    WL[e] = f2bf(w - bf2f(h));
}

// ---------------------------------------------------------------------------
// conv0 + global max via bf16x3 MFMA emulation:
//   W.H ~= Whi.Hhi + Whi.Hlo + Wlo.Hhi  (error ~2^-18 rel per term).
// Block tile: 64 n x 128 f; per wave 32n x 64f = 2x4 16x16x32 tiles, 3 MFMA
// each per 32-c chunk. LDS rows padded to 40 shorts: b128 frag reads spread
// uniformly over all 8 bank-quads (conflict-free).
// ---------------------------------------------------------------------------
__global__ __launch_bounds__(256) void conv0mfma_kernel(const unsigned short* __restrict__ HtH,
                                                        const unsigned short* __restrict__ HtL,
                                                        const unsigned short* __restrict__ WH,
                                                        const unsigned short* __restrict__ WL,
                                                        unsigned* __restrict__ M) {
    const int N = NPTS;
    __shared__ unsigned short HsH[64][40], HsL[64][40], WsH[128][40], WsL[128][40];
    const int n0 = blockIdx.x * 64, f0 = blockIdx.y * 128, b = blockIdx.z;
    const int tid = threadIdx.x;
    const int wave = tid >> 6, lane = tid & 63;
    const int wm = wave & 1, wf = wave >> 1;
    const int row = lane & 15, quad = lane >> 4;
    f32x4 acc[2][4];
#pragma unroll
    for (int i = 0; i < 2; ++i)
#pragma unroll
        for (int j = 0; j < 4; ++j) acc[i][j] = (f32x4){0.f, 0.f, 0.f, 0.f};

    const int hn = tid >> 2, hq = tid & 3;   // H staging: 64 rows x 4 chunks
    const int wfr = tid >> 1, wq = tid & 1;  // W staging: 128 rows x 2 chunks

    for (int c0 = 0; c0 < 320; c0 += 32) {
        {
            const size_t src = ((size_t)b * N + n0 + hn) * 320 + c0 + hq * 8;
            *(int4*)&HsH[hn][hq * 8] = *(const int4*)&HtH[src];
            *(int4*)&HsL[hn][hq * 8] = *(const int4*)&HtL[src];
        }
        {
            const size_t src = (size_t)(f0 + wfr) * 320 + c0 + wq * 16;
            *(int4*)&WsH[wfr][wq * 16]     = *(const int4*)&WH[src];
            *(int4*)&WsH[wfr][wq * 16 + 8] = *(const int4*)&WH[src + 8];
            *(int4*)&WsL[wfr][wq * 16]     = *(const int4*)&WL[src];
            *(int4*)&WsL[wfr][wq * 16 + 8] = *(const int4*)&WL[src + 8];
        }
        __syncthreads();
        bf16x8 aH[2], aL[2];
#pragma unroll
        for (int mt = 0; mt < 2; ++mt) {
            aH[mt] = *(const bf16x8*)&HsH[wm * 32 + mt * 16 + row][quad * 8];
            aL[mt] = *(const bf16x8*)&HsL[wm * 32 + mt * 16 + row][quad * 8];
        }
#pragma unroll
        for (int nt = 0; nt < 4; ++nt) {
            bf16x8 bH = *(const bf16x8*)&WsH[wf * 64 + nt * 16 + row][quad * 8];
            bf16x8 bL = *(const bf16x8*)&WsL[wf * 64 + nt * 16 + row][quad * 8];
#pragma unroll
            for (int mt = 0; mt < 2; ++mt) {
                acc[mt][nt] = __builtin_amdgcn_mfma_f32_16x16x32_bf16(aH[mt], bH, acc[mt][nt], 0, 0, 0);
                acc[mt][nt] = __builtin_amdgcn_mfma_f32_16x16x32_bf16(aH[mt], bL, acc[mt][nt], 0, 0, 0);
                acc[mt][nt] = __builtin_amdgcn_mfma_f32_16x16x32_bf16(aL[mt], bH, acc[mt][nt], 0, 0, 0);
            }
        }
        __syncthreads();
    }
    // D[m=n_pt][col=f]: col = lane&15, row = quad*4 + reg. Max over this
    // wave's 32 n: lane-local (2 mt x 4 regs), then across quads (shfl 16,32).
#pragma unroll
    for (int nt = 0; nt < 4; ++nt) {
        float m = acc[0][nt][0];
#pragma unroll
        for (int r = 1; r < 4; ++r) m = fmaxf(m, acc[0][nt][r]);
#pragma unroll
        for (int r = 0; r < 4; ++r) m = fmaxf(m, acc[1][nt][r]);
        m = fmaxf(m, __shfl_down(m, 16));
        m = fmaxf(m, __shfl_down(m, 32));
        if (quad == 0)
            atomicMax(&M[(b << 10) + f0 + wf * 64 + nt * 16 + row], fenc(m));
    }
}

// ---------------------------------------------------------------------------
// Fused head (unchanged).
// ---------------------------------------------------------------------------
__global__ __launch_bounds__(256) void fc_kernel(const unsigned* __restrict__ M,
    const float* __restrict__ cb, const float* __restrict__ cs, const float* __restrict__ ct,
    const float* __restrict__ w0, const float* __restrict__ b0, const float* __restrict__ s0, const float* __restrict__ t0,
    const float* __restrict__ w1, const float* __restrict__ b1, const float* __restrict__ s1, const float* __restrict__ t1,
    const float* __restrict__ w2, const float* __restrict__ b2, const float* __restrict__ s2, const float* __restrict__ t2,
    float* __restrict__ out) {
    __shared__ float g0[1024], g1[512], g2[256];
    const int b = blockIdx.x, tid = threadIdx.x;
    for (int f = tid; f < 1024; f += 256) {
        float z = fdec(M[b * 1024 + f]);
        float g = cs[f] * (z + cb[f]) + ct[f];
        g0[f] = fmaxf(g, 0.f);
    }
    __syncthreads();
    for (int f = tid; f < 512; f += 256) {
        const float4* wp = (const float4*)(w0 + (size_t)f * 1024);
        float acc = 0.f;
#pragma unroll 4
        for (int c = 0; c < 256; ++c) {
            float4 wv = wp[c];
            float4 gv = *(const float4*)&g0[c * 4];
            acc += wv.x * gv.x + wv.y * gv.y + wv.z * gv.z + wv.w * gv.w;
        }
        float g = s0[f] * (acc + b0[f]) + t0[f];
        g1[f] = fmaxf(g, 0.f);
    }
    __syncthreads();
    if (tid < 256) {
        const float4* wp = (const float4*)(w1 + (size_t)tid * 512);
        float acc = 0.f;
#pragma unroll 4
        for (int c = 0; c < 128; ++c) {
            float4 wv = wp[c];
            float4 gv = *(const float4*)&g1[c * 4];
            acc += wv.x * gv.x + wv.y * gv.y + wv.z * gv.z + wv.w * gv.w;
        }
        float g = s1[tid] * (acc + b1[tid]) + t1[tid];
        g2[tid] = fmaxf(g, 0.f);
    }
    __syncthreads();
    if (tid < 40) {
        const float4* wp = (const float4*)(w2 + (size_t)tid * 256);
        float acc = 0.f;
#pragma unroll 4
        for (int c = 0; c < 64; ++c) {
            float4 wv = wp[c];
            float4 gv = *(const float4*)&g2[c * 4];
            acc += wv.x * gv.x + wv.y * gv.y + wv.z * gv.z + wv.w * gv.w;
        }
        float g = s2[tid] * (acc + b2[tid]) + t2[tid];
        out[b * 40 + tid] = fmaxf(g, 0.f);
    }
}

// ---------------------------------------------------------------------------
extern "C" void kernel_launch(void* const* d_in, const int* in_sizes, int n_in,
                              void* d_out, int out_size, void* d_ws, size_t ws_size,
                              hipStream_t stream) {
    const float* x       = (const float*)d_in[0];
    const float* ec0_w   = (const float*)d_in[1];
    const float* ec0_b   = (const float*)d_in[2];
    const float* ec1_w   = (const float*)d_in[3];
    const float* ec1_b   = (const float*)d_in[4];
    const float* ec2_w   = (const float*)d_in[5];
    const float* ec2_b   = (const float*)d_in[6];
    const float* ec3_w   = (const float*)d_in[7];
    const float* ec3_b   = (const float*)d_in[8];
    const float* conv0_w = (const float*)d_in[9];
    const float* conv0_b = (const float*)d_in[10];
    const float* conv0_s = (const float*)d_in[11];
    const float* conv0_t = (const float*)d_in[12];
    const float* fc0_w   = (const float*)d_in[13];
    const float* fc0_b   = (const float*)d_in[14];
    const float* fc0_s   = (const float*)d_in[15];
    const float* fc0_t   = (const float*)d_in[16];
    const float* fc1_w   = (const float*)d_in[17];
    const float* fc1_b   = (const float*)d_in[18];
    const float* fc1_s   = (const float*)d_in[19];
    const float* fc1_t   = (const float*)d_in[20];
    const float* fc2_w   = (const float*)d_in[21];
    const float* fc2_b   = (const float*)d_in[22];
    const float* fc2_s   = (const float*)d_in[23];
    const float* fc2_t   = (const float*)d_in[24];
    float* out = (float*)d_out;

    char* ws = (char*)d_ws;
    const int B = 16, N = NPTS;
    float* Hc   = (float*)(ws + 0);            // [16][320][2048]  41,943,040 B
    float* U    = (float*)(ws + 41943040);     // [16][2048][128]  16,777,216 B
    float* T    = (float*)(ws + 58720256);     // [16][128][2048]  16,777,216 B
    int*   I    = (int*)  (ws + 75497472);     // [16][2048][20]    2,621,440 B
    unsigned* M = (unsigned*)(ws + 78118912);  // [16][1024]           65,536 B
    unsigned short* W_hi = (unsigned short*)(ws + 78184448);  //  655,360 B
    unsigned short* W_lo = (unsigned short*)(ws + 78839808);  //  655,360 B
    unsigned short* HtH  = (unsigned short*)(ws + 79495168);  // [16][2048][320] 20,971,520 B
    unsigned short* HtL  = (unsigned short*)(ws + 100466688); // [16][2048][320] 20,971,520 B
    // end: 121,438,208 B

    dim3 blk(256);
    const int bsX0 = 3 * N, bsH = 320 * N;

    wsplit_kernel<<<dim3(1024 * 320 / 256), blk, 0, stream>>>(conv0_w, W_hi, W_lo);

    // ---- Layer 0 (C=3 -> F=64) ----
    select0_kernel<<<dim3(B * N / 4), blk, 0, stream>>>(x, I);
    ut_kernel<64, 3><<<dim3(N / 64, 1, B), blk, 0, stream>>>(x, bsX0, ec0_w, ec0_b, U, T);
    gathermax_kernel<64, true><<<dim3(N / 32, B), blk, 0, stream>>>(U, T, I, Hc, bsH, HtH, HtL, 0);

    // ---- Layers 1..3 (C=64): fused dist+select with inline sq ----
    const float* Xin[3] = {Hc, Hc + (size_t)64 * N, Hc + (size_t)128 * N};
    const float* ecw[3] = {ec1_w, ec2_w, ec3_w};
    const float* ecb[3] = {ec1_b, ec2_b, ec3_b};
    for (int L = 0; L < 3; ++L) {
        knnfused_kernel<<<dim3(N / 8, B), blk, 0, stream>>>(Xin[L], bsH, I);
        if (L < 2) {
            ut_kernel<64, 64><<<dim3(N / 64, 1, B), blk, 0, stream>>>(Xin[L], bsH, ecw[L], ecb[L], U, T);
            gathermax_kernel<64, true><<<dim3(N / 32, B), blk, 0, stream>>>(
                U, T, I, Hc + (size_t)(64 * (L + 1)) * N, bsH, HtH, HtL, 64 * (L + 1));
        } else {
            ut_kernel<128, 64><<<dim3(N / 64, 2, B), blk, 0, stream>>>(Xin[L], bsH, ecw[L], ecb[L], U, T);
            gathermax_kernel<128, false><<<dim3(N / 32, B), blk, 0, stream>>>(
                U, T, I, Hc + (size_t)192 * N, bsH, HtH, HtL, 192);
        }
    }

    // ---- conv0 + global max (bf16x3 MFMA) ----
    (void)hipMemsetAsync(M, 0, B * 1024 * sizeof(unsigned), stream);
    conv0mfma_kernel<<<dim3(N / 64, 1024 / 128, B), blk, 0, stream>>>(HtH, HtL, W_hi, W_lo, M);

    // ---- head ----
    fc_kernel<<<dim3(B), blk, 0, stream>>>(M, conv0_b, conv0_s, conv0_t,
                                           fc0_w, fc0_b, fc0_s, fc0_t,
                                           fc1_w, fc1_b, fc1_s, fc1_t,
                                           fc2_w, fc2_b, fc2_s, fc2_t, out);
}

// Round 2
// 1034.863 us; speedup vs baseline: 1.1808x; 1.1808x over previous
//
#include <hip/hip_runtime.h>

#define DEVINL __device__ __forceinline__

static const int NPTS = 2048;

typedef __attribute__((ext_vector_type(8))) short bf16x8;
typedef __attribute__((ext_vector_type(4))) float f32x4;

DEVINL unsigned fenc(float x) {
    int b = __float_as_int(x);
    return (b < 0) ? ~(unsigned)b : ((unsigned)b | 0x80000000u);
}
DEVINL float fdec(unsigned u) {
    return (u & 0x80000000u) ? __int_as_float((int)(u & 0x7fffffffu))
                             : __int_as_float((int)~u);
}
DEVINL unsigned long long u64min(unsigned long long a, unsigned long long b) {
    return (b < a) ? b : a;
}
DEVINL unsigned short f2bf(float x) {  // round-to-nearest-even bf16 (finite inputs)
    unsigned u = __float_as_uint(x);
    return (unsigned short)((u + 0x7fffu + ((u >> 16) & 1u)) >> 16);
}
DEVINL float bf2f(unsigned short h) { return __uint_as_float(((unsigned)h) << 16); }

// ---------------------------------------------------------------------------
// Exact top-20 of a row held as v[32] per lane (col(j) = lane*4+(j&3)+(j>>2)*256).
// tau = 20th smallest of the 64 lane-minima; ballot-compact <=tau (E~25) ->
// u64 bitonic sort -> lanes 0..19. Fallback to 20x tournament when >64 cands.
// ---------------------------------------------------------------------------
DEVINL void topk20(float v[32], unsigned long long* cand, int lane,
                   int* __restrict__ Iout, int outBase) {
    float t16[16];
#pragma unroll
    for (int i = 0; i < 16; ++i) t16[i] = fminf(v[i], v[i + 16]);
#pragma unroll
    for (int i = 0; i < 8; ++i) t16[i] = fminf(t16[i], t16[i + 8]);
#pragma unroll
    for (int i = 0; i < 4; ++i) t16[i] = fminf(t16[i], t16[i + 4]);
    float s = fminf(fminf(t16[0], t16[1]), fminf(t16[2], t16[3]));
#pragma unroll
    for (int k = 2; k <= 64; k <<= 1) {
#pragma unroll
        for (int j = k >> 1; j >= 1; j >>= 1) {
            float o = __shfl_xor(s, j);
            bool keepmin = (((lane & j) == 0) == ((lane & k) == 0));
            s = keepmin ? fminf(s, o) : fmaxf(s, o);
        }
    }
    const float tau = __shfl(s, 19);
    int cnt = 0;
#pragma unroll
    for (int j = 0; j < 32; ++j) {
        bool pass = (v[j] <= tau);
        unsigned long long mask = __ballot(pass);
        if (pass) {
            int pos = cnt + (int)__popcll(mask & ((1ull << lane) - 1ull));
            if (pos < 64) {
                int col = lane * 4 + (j & 3) + ((j >> 2) << 8);
                cand[pos] = ((unsigned long long)fenc(v[j]) << 32) | (unsigned)col;
            }
        }
        cnt += (int)__popcll(mask);
    }
    if (cnt <= 64) {
        unsigned long long key = (lane < cnt) ? cand[lane] : ~0ull;
#pragma unroll
        for (int k = 2; k <= 64; k <<= 1) {
#pragma unroll
            for (int j = k >> 1; j >= 1; j >>= 1) {
                unsigned long long o = __shfl_xor(key, j);
                bool keepmin = (((lane & j) == 0) == ((lane & k) == 0));
                unsigned long long mn = u64min(key, o);
                unsigned long long mx = (key ^ o) ^ mn;
                key = keepmin ? mn : mx;
            }
        }
        if (lane < 20) Iout[outBase + lane] = (int)(unsigned)(key & 0xffffffffu);
    } else {
        unsigned long long vk[32];
#pragma unroll
        for (int j = 0; j < 32; ++j) {
            int col = lane * 4 + (j & 3) + ((j >> 2) << 8);
            vk[j] = ((unsigned long long)fenc(v[j]) << 32) | (unsigned)col;
        }
        unsigned long long last = 0ull;
        for (int it = 0; it < 20; ++it) {
            unsigned long long q16[16];
#pragma unroll
            for (int i = 0; i < 16; ++i) {
                unsigned long long a = (vk[i] > last) ? vk[i] : ~0ull;
                unsigned long long c = (vk[i + 16] > last) ? vk[i + 16] : ~0ull;
                q16[i] = u64min(a, c);
            }
#pragma unroll
            for (int i = 0; i < 8; ++i) q16[i] = u64min(q16[i], q16[i + 8]);
#pragma unroll
            for (int i = 0; i < 4; ++i) q16[i] = u64min(q16[i], q16[i + 4]);
            unsigned long long best = u64min(u64min(q16[0], q16[1]), u64min(q16[2], q16[3]));
#pragma unroll
            for (int off = 32; off >= 1; off >>= 1) {
                unsigned long long o = __shfl_down(best, off);
                best = u64min(best, o);
            }
            best = __shfl(best, 0);
            if (lane == 0) Iout[outBase + it] = (int)(unsigned)(best & 0xffffffffu);
            last = best;
        }
    }
}

// ---------------------------------------------------------------------------
// Fused KNN (C=64) with inline sq: block owns 8 rows; GEMM 8x2048x64 with A in
// LDS, B streamed (L2-resident); sq[m] accumulated per-thread alongside (same
// ascending-c order as the baseline -> bit-identical distances).
// 512 threads/block: each thread owns 4 columns (acc[8][4]=32 VGPR, no live
// accs across topk, no spills); 8 waves -> one topk row per wave. LDS 70 KB
// -> 2 blocks/CU but 16 waves/CU = 4 waves/SIMD (2x the 995us baseline's
// occupancy) with the baseline's register pressure. Bit-identical output.
// ---------------------------------------------------------------------------
__global__ __launch_bounds__(512, 4) void knnfused_kernel(const float* __restrict__ X, int bs,
                                                          int* __restrict__ Iout) {
    extern __shared__ char smem[];
    float* Dr = (float*)smem;                                       // [8][2048] 64 KB
    float* As = (float*)(smem + 65536);                             // [64][8]    2 KB
    unsigned long long* cand = (unsigned long long*)(smem + 67584); // [8][64]    4 KB
    const int N = NPTS, K = 20;
    const int b = blockIdx.y, n0 = blockIdx.x * 8;
    const float* __restrict__ Xb = X + (size_t)b * bs;
    const int tid = threadIdx.x;
    if (tid < 128) {
        int c = tid >> 1, r4 = (tid & 1) * 4;
        *(float4*)&As[c * 8 + r4] = *(const float4*)&Xb[(size_t)c * N + n0 + r4];
    }
    __syncthreads();
    const int m0 = tid * 4;
    float acc[8][4], sq[4];
#pragma unroll
    for (int r = 0; r < 8; ++r)
#pragma unroll
        for (int j = 0; j < 4; ++j) acc[r][j] = 0.f;
#pragma unroll
    for (int j = 0; j < 4; ++j) sq[j] = 0.f;
#pragma unroll 4
    for (int c = 0; c < 64; ++c) {
        float4 b0 = *(const float4*)&Xb[(size_t)c * N + m0];
        float4 a0 = *(const float4*)&As[c * 8];
        float4 a1 = *(const float4*)&As[c * 8 + 4];
        sq[0] += b0.x * b0.x; sq[1] += b0.y * b0.y;
        sq[2] += b0.z * b0.z; sq[3] += b0.w * b0.w;
        float av[8] = {a0.x, a0.y, a0.z, a0.w, a1.x, a1.y, a1.z, a1.w};
#pragma unroll
        for (int r = 0; r < 8; ++r) {
            acc[r][0] += av[r] * b0.x; acc[r][1] += av[r] * b0.y;
            acc[r][2] += av[r] * b0.z; acc[r][3] += av[r] * b0.w;
        }
    }
    const float INF = __builtin_inff();
#pragma unroll
    for (int r = 0; r < 8; ++r) {
        const int n = n0 + r;
        float d0[4] = {sq[0] - 2.f * acc[r][0], sq[1] - 2.f * acc[r][1],
                       sq[2] - 2.f * acc[r][2], sq[3] - 2.f * acc[r][3]};
#pragma unroll
        for (int j = 0; j < 4; ++j) {
            if (m0 + j == n) d0[j] = INF;
        }
        *(float4*)&Dr[r * N + m0] = make_float4(d0[0], d0[1], d0[2], d0[3]);
    }
    __syncthreads();
    const int w = tid >> 6, lane = tid & 63;
    const float* __restrict__ rp = &Dr[w * N];
    float v[32];
#pragma unroll
    for (int q = 0; q < 8; ++q) {
        float4 x4 = *(const float4*)&rp[lane * 4 + q * 256];
        v[q * 4 + 0] = x4.x; v[q * 4 + 1] = x4.y;
        v[q * 4 + 2] = x4.z; v[q * 4 + 3] = x4.w;
    }
    topk20(v, cand + w * 64, lane, Iout, (b * N + n0 + w) * K);
}

// ---------------------------------------------------------------------------
// select0: layer-0 (C=3) — scores inline, register topk.
// ---------------------------------------------------------------------------
__global__ __launch_bounds__(256) void select0_kernel(const float* __restrict__ X,
                                                      int* __restrict__ Iout) {
    const int N = NPTS, K = 20;
    __shared__ unsigned long long cand[4][64];
    const int w = threadIdx.x >> 6, lane = threadIdx.x & 63;
    const int rowg = blockIdx.x * 4 + w;
    const int b = rowg >> 11, n = rowg & 2047;
    const float* __restrict__ Xb = X + (size_t)b * 3 * N;
    const float xr = Xb[n], yr = Xb[N + n], zr = Xb[2 * N + n];
    const float INF = __builtin_inff();
    float v[32];
#pragma unroll
    for (int q = 0; q < 8; ++q) {
        const int base = lane * 4 + q * 256;
        const float4 xm = *(const float4*)&Xb[base];
        const float4 ym = *(const float4*)&Xb[N + base];
        const float4 zm = *(const float4*)&Xb[2 * N + base];
        float mx[4] = {xm.x, xm.y, xm.z, xm.w};
        float my[4] = {ym.x, ym.y, ym.z, ym.w};
        float mz[4] = {zm.x, zm.y, zm.z, zm.w};
#pragma unroll
        for (int j = 0; j < 4; ++j) {
            float sq = mx[j] * mx[j] + my[j] * my[j] + mz[j] * mz[j];
            float dot = xr * mx[j] + yr * my[j] + zr * mz[j];
            float d = sq - 2.f * dot;
            v[q * 4 + j] = (base + j == n) ? INF : d;
        }
    }
    topk20(v, &cand[w][0], lane, Iout, (b * N + n) * K);
}

// ---------------------------------------------------------------------------
// U/T GEMMs (unchanged).
// ---------------------------------------------------------------------------
template<int F, int C>
__global__ __launch_bounds__(256) void ut_kernel(const float* __restrict__ X, int bs,
                                                 const float* __restrict__ W,
                                                 const float* __restrict__ bias,
                                                 float* __restrict__ U, float* __restrict__ T) {
    const int N = NPTS;
    __shared__ float Ws2[64][C + 1];
    __shared__ float Wsd[64][C + 1];
    const int n0 = blockIdx.x * 64, f0 = blockIdx.y * 64, b = blockIdx.z;
    const int tid = threadIdx.x;
    for (int i = tid; i < 64 * C; i += 256) {
        int ff = i / C, c = i - ff * C;
        float w1 = W[(f0 + ff) * (2 * C) + c];
        float w2 = W[(f0 + ff) * (2 * C) + C + c];
        Ws2[ff][c] = w2;
        Wsd[ff][c] = w1 - w2;
    }
    __syncthreads();
    const int nt = tid & 15, fg = tid >> 4;
    const float* __restrict__ Xb = X + (size_t)b * bs;
    float au[4][4], av[4][4];
#pragma unroll
    for (int i = 0; i < 4; ++i)
#pragma unroll
        for (int j = 0; j < 4; ++j) { au[i][j] = 0.f; av[i][j] = 0.f; }
#pragma unroll 4
    for (int c = 0; c < C; ++c) {
        const float4 xv = *(const float4*)&Xb[(size_t)c * N + n0 + nt * 4];
#pragma unroll
        for (int fi = 0; fi < 4; ++fi) {
            float w2v = Ws2[fg * 4 + fi][c];
            float wdv = Wsd[fg * 4 + fi][c];
            au[fi][0] += w2v * xv.x; au[fi][1] += w2v * xv.y;
            au[fi][2] += w2v * xv.z; au[fi][3] += w2v * xv.w;
            av[fi][0] += wdv * xv.x; av[fi][1] += wdv * xv.y;
            av[fi][2] += wdv * xv.z; av[fi][3] += wdv * xv.w;
        }
    }
#pragma unroll
    for (int ni = 0; ni < 4; ++ni) {
        int n = n0 + nt * 4 + ni;
        float4 uv = make_float4(au[0][ni], au[1][ni], au[2][ni], au[3][ni]);
        *(float4*)&U[((size_t)b * N + n) * F + f0 + fg * 4] = uv;
    }
#pragma unroll
    for (int fi = 0; fi < 4; ++fi) {
        int f = f0 + fg * 4 + fi;
        float bv = bias[f];
        float4 tv = make_float4(av[fi][0] + bv, av[fi][1] + bv, av[fi][2] + bv, av[fi][3] + bv);
        *(float4*)&T[((size_t)b * F + f) * N + n0 + nt * 4] = tv;
    }
}

// ---------------------------------------------------------------------------
// Gather-max: block = 32 points x 8 f-groups. Writes fp32 Hc slice (optional,
// needed as next-layer KNN input) AND bf16 hi/lo into Ht[b][n][320] at column
// offset `hoff` (c-contiguous — the MFMA A-operand layout for conv0).
// ---------------------------------------------------------------------------
template<int F, bool WRITE_F32>
__global__ __launch_bounds__(256) void gathermax_kernel(const float* __restrict__ U,
                                                        const float* __restrict__ T,
                                                        const int* __restrict__ idx,
                                                        float* __restrict__ Y, int bsY,
                                                        unsigned short* __restrict__ HtH,
                                                        unsigned short* __restrict__ HtL,
                                                        int hoff) {
    const int N = NPTS, K = 20, FG = F / 8;
    __shared__ int sidx[32 * 20];
    const int b = blockIdx.y, n0 = blockIdx.x * 32, tid = threadIdx.x;
    const int p = tid >> 3, fg = tid & 7;
    for (int t = tid; t < 32 * K; t += 256) sidx[t] = idx[(b * N + n0) * K + t];
    __syncthreads();
    const int n = n0 + p;
    const float* __restrict__ Ub = U + (size_t)b * N * F;
    const int fbase = fg * FG;
    float mx[FG];
#pragma unroll
    for (int i = 0; i < FG; ++i) mx[i] = -__builtin_inff();
#pragma unroll 4
    for (int j = 0; j < K; ++j) {
        const int r = sidx[p * K + j];
        const float4* up = (const float4*)&Ub[(size_t)r * F + fbase];
#pragma unroll
        for (int q = 0; q < FG / 4; ++q) {
            float4 a = up[q];
            mx[q * 4 + 0] = fmaxf(mx[q * 4 + 0], a.x);
            mx[q * 4 + 1] = fmaxf(mx[q * 4 + 1], a.y);
            mx[q * 4 + 2] = fmaxf(mx[q * 4 + 2], a.z);
            mx[q * 4 + 3] = fmaxf(mx[q * 4 + 3], a.w);
        }
    }
    float val[FG];
#pragma unroll
    for (int i = 0; i < FG; ++i) {
        const int f = fbase + i;
        val[i] = T[((size_t)b * F + f) * N + n] + mx[i];
        if (WRITE_F32) Y[(size_t)b * bsY + (size_t)f * N + n] = val[i];
    }
    // bf16 hi/lo split, c-contiguous at Ht[b][n][hoff + fbase ...]
    unsigned short hs[FG], ls[FG];
#pragma unroll
    for (int i = 0; i < FG; ++i) {
        unsigned short h = f2bf(val[i]);
        hs[i] = h;
        ls[i] = f2bf(val[i] - bf2f(h));
    }
    const size_t hb = ((size_t)b * N + n) * 320 + hoff + fbase;
#pragma unroll
    for (int q = 0; q < FG / 8; ++q) {
        *(int4*)&HtH[hb + q * 8] = *(const int4*)&hs[q * 8];
        *(int4*)&HtL[hb + q * 8] = *(const int4*)&ls[q * 8];
    }
}

// ---------------------------------------------------------------------------
// conv0_w -> bf16 hi/lo split (one-shot, 1024x320 elements).
// ---------------------------------------------------------------------------
__global__ __launch_bounds__(256) void wsplit_kernel(const float* __restrict__ W,
                                                     unsigned short* __restrict__ WH,
                                                     unsigned short* __restrict__ WL) {
    const int e = blockIdx.x * 256 + threadIdx.x;
    float w = W[e];
    unsigned short h = f2bf(w);
    WH[e] = h;
    WL[e] = f2bf(w - bf2f(h));
}

// ---------------------------------------------------------------------------
// conv0 + global max via bf16x3 MFMA emulation:
//   W.H ~= Whi.Hhi + Whi.Hlo + Wlo.Hhi  (error ~2^-18 rel per term).
// Block tile: 64 n x 128 f; per wave 32n x 64f = 2x4 16x16x32 tiles, 3 MFMA
// each per 32-c chunk. LDS rows padded to 40 shorts: b128 frag reads spread
// uniformly over all 8 bank-quads (conflict-free).
// ---------------------------------------------------------------------------
__global__ __launch_bounds__(256) void conv0mfma_kernel(const unsigned short* __restrict__ HtH,
                                                        const unsigned short* __restrict__ HtL,
                                                        const unsigned short* __restrict__ WH,
                                                        const unsigned short* __restrict__ WL,
                                                        unsigned* __restrict__ M) {
    const int N = NPTS;
    __shared__ unsigned short HsH[64][40], HsL[64][40], WsH[128][40], WsL[128][40];
    const int n0 = blockIdx.x * 64, f0 = blockIdx.y * 128, b = blockIdx.z;
    const int tid = threadIdx.x;
    const int wave = tid >> 6, lane = tid & 63;
    const int wm = wave & 1, wf = wave >> 1;
    const int row = lane & 15, quad = lane >> 4;
    f32x4 acc[2][4];
#pragma unroll
    for (int i = 0; i < 2; ++i)
#pragma unroll
        for (int j = 0; j < 4; ++j) acc[i][j] = (f32x4){0.f, 0.f, 0.f, 0.f};

    const int hn = tid >> 2, hq = tid & 3;   // H staging: 64 rows x 4 chunks
    const int wfr = tid >> 1, wq = tid & 1;  // W staging: 128 rows x 2 chunks

    for (int c0 = 0; c0 < 320; c0 += 32) {
        {
            const size_t src = ((size_t)b * N + n0 + hn) * 320 + c0 + hq * 8;
            *(int4*)&HsH[hn][hq * 8] = *(const int4*)&HtH[src];
            *(int4*)&HsL[hn][hq * 8] = *(const int4*)&HtL[src];
        }
        {
            const size_t src = (size_t)(f0 + wfr) * 320 + c0 + wq * 16;
            *(int4*)&WsH[wfr][wq * 16]     = *(const int4*)&WH[src];
            *(int4*)&WsH[wfr][wq * 16 + 8] = *(const int4*)&WH[src + 8];
            *(int4*)&WsL[wfr][wq * 16]     = *(const int4*)&WL[src];
            *(int4*)&WsL[wfr][wq * 16 + 8] = *(const int4*)&WL[src + 8];
        }
        __syncthreads();
        bf16x8 aH[2], aL[2];
#pragma unroll
        for (int mt = 0; mt < 2; ++mt) {
            aH[mt] = *(const bf16x8*)&HsH[wm * 32 + mt * 16 + row][quad * 8];
            aL[mt] = *(const bf16x8*)&HsL[wm * 32 + mt * 16 + row][quad * 8];
        }
#pragma unroll
        for (int nt = 0; nt < 4; ++nt) {
            bf16x8 bH = *(const bf16x8*)&WsH[wf * 64 + nt * 16 + row][quad * 8];
            bf16x8 bL = *(const bf16x8*)&WsL[wf * 64 + nt * 16 + row][quad * 8];
#pragma unroll
            for (int mt = 0; mt < 2; ++mt) {
                acc[mt][nt] = __builtin_amdgcn_mfma_f32_16x16x32_bf16(aH[mt], bH, acc[mt][nt], 0, 0, 0);
                acc[mt][nt] = __builtin_amdgcn_mfma_f32_16x16x32_bf16(aH[mt], bL, acc[mt][nt], 0, 0, 0);
                acc[mt][nt] = __builtin_amdgcn_mfma_f32_16x16x32_bf16(aL[mt], bH, acc[mt][nt], 0, 0, 0);
            }
        }
        __syncthreads();
    }
    // D[m=n_pt][col=f]: col = lane&15, row = quad*4 + reg. Max over this
    // wave's 32 n: lane-local (2 mt x 4 regs), then across quads (shfl 16,32).
#pragma unroll
    for (int nt = 0; nt < 4; ++nt) {
        float m = acc[0][nt][0];
#pragma unroll
        for (int r = 1; r < 4; ++r) m = fmaxf(m, acc[0][nt][r]);
#pragma unroll
        for (int r = 0; r < 4; ++r) m = fmaxf(m, acc[1][nt][r]);
        m = fmaxf(m, __shfl_down(m, 16));
        m = fmaxf(m, __shfl_down(m, 32));
        if (quad == 0)
            atomicMax(&M[(b << 10) + f0 + wf * 64 + nt * 16 + row], fenc(m));
    }
}

// ---------------------------------------------------------------------------
// Fused head (unchanged).
// ---------------------------------------------------------------------------
__global__ __launch_bounds__(256) void fc_kernel(const unsigned* __restrict__ M,
    const float* __restrict__ cb, const float* __restrict__ cs, const float* __restrict__ ct,
    const float* __restrict__ w0, const float* __restrict__ b0, const float* __restrict__ s0, const float* __restrict__ t0,
    const float* __restrict__ w1, const float* __restrict__ b1, const float* __restrict__ s1, const float* __restrict__ t1,
    const float* __restrict__ w2, const float* __restrict__ b2, const float* __restrict__ s2, const float* __restrict__ t2,
    float* __restrict__ out) {
    __shared__ float g0[1024], g1[512], g2[256];
    const int b = blockIdx.x, tid = threadIdx.x;
    for (int f = tid; f < 1024; f += 256) {
        float z = fdec(M[b * 1024 + f]);
        float g = cs[f] * (z + cb[f]) + ct[f];
        g0[f] = fmaxf(g, 0.f);
    }
    __syncthreads();
    for (int f = tid; f < 512; f += 256) {
        const float4* wp = (const float4*)(w0 + (size_t)f * 1024);
        float acc = 0.f;
#pragma unroll 4
        for (int c = 0; c < 256; ++c) {
            float4 wv = wp[c];
            float4 gv = *(const float4*)&g0[c * 4];
            acc += wv.x * gv.x + wv.y * gv.y + wv.z * gv.z + wv.w * gv.w;
        }
        float g = s0[f] * (acc + b0[f]) + t0[f];
        g1[f] = fmaxf(g, 0.f);
    }
    __syncthreads();
    if (tid < 256) {
        const float4* wp = (const float4*)(w1 + (size_t)tid * 512);
        float acc = 0.f;
#pragma unroll 4
        for (int c = 0; c < 128; ++c) {
            float4 wv = wp[c];
            float4 gv = *(const float4*)&g1[c * 4];
            acc += wv.x * gv.x + wv.y * gv.y + wv.z * gv.z + wv.w * gv.w;
        }
        float g = s1[tid] * (acc + b1[tid]) + t1[tid];
        g2[tid] = fmaxf(g, 0.f);
    }
    __syncthreads();
    if (tid < 40) {
        const float4* wp = (const float4*)(w2 + (size_t)tid * 256);
        float acc = 0.f;
#pragma unroll 4
        for (int c = 0; c < 64; ++c) {
            float4 wv = wp[c];
            float4 gv = *(const float4*)&g2[c * 4];
            acc += wv.x * gv.x + wv.y * gv.y + wv.z * gv.z + wv.w * gv.w;
        }
        float g = s2[tid] * (acc + b2[tid]) + t2[tid];
        out[b * 40 + tid] = fmaxf(g, 0.f);
    }
}

// ---------------------------------------------------------------------------
extern "C" void kernel_launch(void* const* d_in, const int* in_sizes, int n_in,
                              void* d_out, int out_size, void* d_ws, size_t ws_size,
                              hipStream_t stream) {
    const float* x       = (const float*)d_in[0];
    const float* ec0_w   = (const float*)d_in[1];
    const float* ec0_b   = (const float*)d_in[2];
    const float* ec1_w   = (const float*)d_in[3];
    const float* ec1_b   = (const float*)d_in[4];
    const float* ec2_w   = (const float*)d_in[5];
    const float* ec2_b   = (const float*)d_in[6];
    const float* ec3_w   = (const float*)d_in[7];
    const float* ec3_b   = (const float*)d_in[8];
    const float* conv0_w = (const float*)d_in[9];
    const float* conv0_b = (const float*)d_in[10];
    const float* conv0_s = (const float*)d_in[11];
    const float* conv0_t = (const float*)d_in[12];
    const float* fc0_w   = (const float*)d_in[13];
    const float* fc0_b   = (const float*)d_in[14];
    const float* fc0_s   = (const float*)d_in[15];
    const float* fc0_t   = (const float*)d_in[16];
    const float* fc1_w   = (const float*)d_in[17];
    const float* fc1_b   = (const float*)d_in[18];
    const float* fc1_s   = (const float*)d_in[19];
    const float* fc1_t   = (const float*)d_in[20];
    const float* fc2_w   = (const float*)d_in[21];
    const float* fc2_b   = (const float*)d_in[22];
    const float* fc2_s   = (const float*)d_in[23];
    const float* fc2_t   = (const float*)d_in[24];
    float* out = (float*)d_out;

    char* ws = (char*)d_ws;
    const int B = 16, N = NPTS;
    float* Hc   = (float*)(ws + 0);            // [16][320][2048]  41,943,040 B
    float* U    = (float*)(ws + 41943040);     // [16][2048][128]  16,777,216 B
    float* T    = (float*)(ws + 58720256);     // [16][128][2048]  16,777,216 B
    int*   I    = (int*)  (ws + 75497472);     // [16][2048][20]    2,621,440 B
    unsigned* M = (unsigned*)(ws + 78118912);  // [16][1024]           65,536 B
    unsigned short* W_hi = (unsigned short*)(ws + 78184448);  //  655,360 B
    unsigned short* W_lo = (unsigned short*)(ws + 78839808);  //  655,360 B
    unsigned short* HtH  = (unsigned short*)(ws + 79495168);  // [16][2048][320] 20,971,520 B
    unsigned short* HtL  = (unsigned short*)(ws + 100466688); // [16][2048][320] 20,971,520 B
    // end: 121,438,208 B

    (void)hipFuncSetAttribute((const void*)knnfused_kernel,
                              hipFuncAttributeMaxDynamicSharedMemorySize, 71680);

    dim3 blk(256);
    const int bsX0 = 3 * N, bsH = 320 * N;

    wsplit_kernel<<<dim3(1024 * 320 / 256), blk, 0, stream>>>(conv0_w, W_hi, W_lo);

    // ---- Layer 0 (C=3 -> F=64) ----
    select0_kernel<<<dim3(B * N / 4), blk, 0, stream>>>(x, I);
    ut_kernel<64, 3><<<dim3(N / 64, 1, B), blk, 0, stream>>>(x, bsX0, ec0_w, ec0_b, U, T);
    gathermax_kernel<64, true><<<dim3(N / 32, B), blk, 0, stream>>>(U, T, I, Hc, bsH, HtH, HtL, 0);

    // ---- Layers 1..3 (C=64): fused dist+select with inline sq ----
    const float* Xin[3] = {Hc, Hc + (size_t)64 * N, Hc + (size_t)128 * N};
    const float* ecw[3] = {ec1_w, ec2_w, ec3_w};
    const float* ecb[3] = {ec1_b, ec2_b, ec3_b};
    for (int L = 0; L < 3; ++L) {
        knnfused_kernel<<<dim3(N / 8, B), dim3(512), 71680, stream>>>(Xin[L], bsH, I);
        if (L < 2) {
            ut_kernel<64, 64><<<dim3(N / 64, 1, B), blk, 0, stream>>>(Xin[L], bsH, ecw[L], ecb[L], U, T);
            gathermax_kernel<64, true><<<dim3(N / 32, B), blk, 0, stream>>>(
                U, T, I, Hc + (size_t)(64 * (L + 1)) * N, bsH, HtH, HtL, 64 * (L + 1));
        } else {
            ut_kernel<128, 64><<<dim3(N / 64, 2, B), blk, 0, stream>>>(Xin[L], bsH, ecw[L], ecb[L], U, T);
            gathermax_kernel<128, false><<<dim3(N / 32, B), blk, 0, stream>>>(
                U, T, I, Hc + (size_t)192 * N, bsH, HtH, HtL, 192);
        }
    }

    // ---- conv0 + global max (bf16x3 MFMA) ----
    (void)hipMemsetAsync(M, 0, B * 1024 * sizeof(unsigned), stream);
    conv0mfma_kernel<<<dim3(N / 64, 1024 / 128, B), blk, 0, stream>>>(HtH, HtL, W_hi, W_lo, M);

    // ---- head ----
    fc_kernel<<<dim3(B), blk, 0, stream>>>(M, conv0_b, conv0_s, conv0_t,
                                           fc0_w, fc0_b, fc0_s, fc0_t,
                                           fc1_w, fc1_b, fc1_s, fc1_t,
                                           fc2_w, fc2_b, fc2_s, fc2_t, out);
}

// Round 3
// 966.936 us; speedup vs baseline: 1.2638x; 1.0702x over previous
//
#include <hip/hip_runtime.h>

#define DEVINL __device__ __forceinline__

static const int NPTS = 2048;

typedef __attribute__((ext_vector_type(8))) short bf16x8;
typedef __attribute__((ext_vector_type(4))) float f32x4;

DEVINL unsigned fenc(float x) {
    int b = __float_as_int(x);
    return (b < 0) ? ~(unsigned)b : ((unsigned)b | 0x80000000u);
}
DEVINL float fdec(unsigned u) {
    return (u & 0x80000000u) ? __int_as_float((int)(u & 0x7fffffffu))
                             : __int_as_float((int)~u);
}
DEVINL unsigned long long u64min(unsigned long long a, unsigned long long b) {
    return (b < a) ? b : a;
}
DEVINL unsigned short f2bf(float x) {  // round-to-nearest-even bf16 (finite inputs)
    unsigned u = __float_as_uint(x);
    return (unsigned short)((u + 0x7fffu + ((u >> 16) & 1u)) >> 16);
}
DEVINL float bf2f(unsigned short h) { return __uint_as_float(((unsigned)h) << 16); }

// ---------------------------------------------------------------------------
// Exact top-20 of a row held as v[32] per lane (col(j) = lane*4+(j&3)+(j>>2)*256).
// tau = 20th smallest of the 64 lane-minima; ballot-compact <=tau (E~25) ->
// u64 bitonic sort -> lanes 0..19. Fallback (>64 cands, ~never): low-register
// 20-round lexicographic (fenc(v), col) tournament with a taken-bitmask —
// identical ordering to the old u64-key tournament ((fenc<<32)|col) but needs
// ~8 extra VGPRs instead of 64 (rd1's spill cause).
// ---------------------------------------------------------------------------
DEVINL void topk20(float v[32], unsigned long long* cand, int lane,
                   int* __restrict__ Iout, int outBase) {
    float t16[16];
#pragma unroll
    for (int i = 0; i < 16; ++i) t16[i] = fminf(v[i], v[i + 16]);
#pragma unroll
    for (int i = 0; i < 8; ++i) t16[i] = fminf(t16[i], t16[i + 8]);
#pragma unroll
    for (int i = 0; i < 4; ++i) t16[i] = fminf(t16[i], t16[i + 4]);
    float s = fminf(fminf(t16[0], t16[1]), fminf(t16[2], t16[3]));
#pragma unroll
    for (int k = 2; k <= 64; k <<= 1) {
#pragma unroll
        for (int j = k >> 1; j >= 1; j >>= 1) {
            float o = __shfl_xor(s, j);
            bool keepmin = (((lane & j) == 0) == ((lane & k) == 0));
            s = keepmin ? fminf(s, o) : fmaxf(s, o);
        }
    }
    const float tau = __shfl(s, 19);
    int cnt = 0;
#pragma unroll
    for (int j = 0; j < 32; ++j) {
        bool pass = (v[j] <= tau);
        unsigned long long mask = __ballot(pass);
        if (pass) {
            int pos = cnt + (int)__popcll(mask & ((1ull << lane) - 1ull));
            if (pos < 64) {
                int col = lane * 4 + (j & 3) + ((j >> 2) << 8);
                cand[pos] = ((unsigned long long)fenc(v[j]) << 32) | (unsigned)col;
            }
        }
        cnt += (int)__popcll(mask);
    }
    if (cnt <= 64) {
        unsigned long long key = (lane < cnt) ? cand[lane] : ~0ull;
#pragma unroll
        for (int k = 2; k <= 64; k <<= 1) {
#pragma unroll
            for (int j = k >> 1; j >= 1; j >>= 1) {
                unsigned long long o = __shfl_xor(key, j);
                bool keepmin = (((lane & j) == 0) == ((lane & k) == 0));
                unsigned long long mn = u64min(key, o);
                unsigned long long mx = (key ^ o) ^ mn;
                key = keepmin ? mn : mx;
            }
        }
        if (lane < 20) Iout[outBase + lane] = (int)(unsigned)(key & 0xffffffffu);
    } else {
        // Cold exact path: 20 rounds of global lex-min over (fenc(v), col).
        unsigned vu[32];
#pragma unroll
        for (int j = 0; j < 32; ++j) vu[j] = fenc(v[j]);
        unsigned taken = 0u;
        for (int it = 0; it < 20; ++it) {
            unsigned bk = 0xffffffffu;
            int bc = 0x7fffffff, bj = 0;
#pragma unroll
            for (int j = 0; j < 32; ++j) {
                const int col = lane * 4 + (j & 3) + ((j >> 2) << 8);
                bool avail = ((taken >> j) & 1u) == 0u;
                bool better = avail && (vu[j] < bk || (vu[j] == bk && col < bc));
                bk = better ? vu[j] : bk;
                bc = better ? col : bc;
                bj = better ? j : bj;
            }
            const int lbc = bc;  // lane-local winner col (unique across lanes)
#pragma unroll
            for (int off = 32; off >= 1; off >>= 1) {
                unsigned ok = __shfl_xor(bk, off);
                int oc = __shfl_xor(bc, off);
                bool t = (ok < bk) || (ok == bk && oc < bc);
                bk = t ? ok : bk;
                bc = t ? oc : bc;
            }
            if (lane == 0) Iout[outBase + it] = bc;
            if (lbc == bc) taken |= (1u << bj);
        }
    }
}

// ---------------------------------------------------------------------------
// Fused KNN (C=64) with inline sq: block owns 16 rows; GEMM 16x2048x64 with A
// in LDS, B streamed. Doubling rows/block halves the streamed-B L2 traffic
// (each loaded B float now feeds 16 rows) — the rd0/rd2 invariant 214 us at
// both 22% and 42% occupancy pinned the kernel as traffic-bound, not VALU- or
// latency-bound. Same ascending-c FMA order -> bit-identical distances.
// Topk in 2 passes over Dr[8][2048]; rows 8-15 are converted to d-values and
// WRITTEN TO Dr BEFORE the first topk, so no registers are held across topk
// (rd1's spill trap avoided structurally).
// ---------------------------------------------------------------------------
__global__ __launch_bounds__(512, 4) void knnfused_kernel(const float* __restrict__ X, int bs,
                                                          int* __restrict__ Iout) {
    extern __shared__ char smem[];
    float* Dr = (float*)smem;                                       // [8][2048] 64 KB
    float* As = (float*)(smem + 65536);                             // [64][16]   4 KB
    unsigned long long* cand = (unsigned long long*)(smem + 69632); // [8][64]    4 KB
    const int N = NPTS, K = 20;
    const int b = blockIdx.y, n0 = blockIdx.x * 16;
    const float* __restrict__ Xb = X + (size_t)b * bs;
    const int tid = threadIdx.x;
    if (tid < 256) {
        int c = tid >> 2, r4 = (tid & 3) * 4;
        *(float4*)&As[c * 16 + r4] = *(const float4*)&Xb[(size_t)c * N + n0 + r4];
    }
    __syncthreads();
    const int m0 = tid * 4;
    float acc[16][4], sq[4];
#pragma unroll
    for (int r = 0; r < 16; ++r)
#pragma unroll
        for (int j = 0; j < 4; ++j) acc[r][j] = 0.f;
#pragma unroll
    for (int j = 0; j < 4; ++j) sq[j] = 0.f;
#pragma unroll 4
    for (int c = 0; c < 64; ++c) {
        float4 b0 = *(const float4*)&Xb[(size_t)c * N + m0];
        float4 a0 = *(const float4*)&As[c * 16];
        float4 a1 = *(const float4*)&As[c * 16 + 4];
        float4 a2 = *(const float4*)&As[c * 16 + 8];
        float4 a3 = *(const float4*)&As[c * 16 + 12];
        sq[0] += b0.x * b0.x; sq[1] += b0.y * b0.y;
        sq[2] += b0.z * b0.z; sq[3] += b0.w * b0.w;
        float av[16] = {a0.x, a0.y, a0.z, a0.w, a1.x, a1.y, a1.z, a1.w,
                        a2.x, a2.y, a2.z, a2.w, a3.x, a3.y, a3.z, a3.w};
#pragma unroll
        for (int r = 0; r < 16; ++r) {
            acc[r][0] += av[r] * b0.x; acc[r][1] += av[r] * b0.y;
            acc[r][2] += av[r] * b0.z; acc[r][3] += av[r] * b0.w;
        }
    }
    const float INF = __builtin_inff();
    // ---- rows 0..7: d -> Dr ----
#pragma unroll
    for (int r = 0; r < 8; ++r) {
        const int n = n0 + r;
        float d0[4] = {sq[0] - 2.f * acc[r][0], sq[1] - 2.f * acc[r][1],
                       sq[2] - 2.f * acc[r][2], sq[3] - 2.f * acc[r][3]};
#pragma unroll
        for (int j = 0; j < 4; ++j) {
            if (m0 + j == n) d0[j] = INF;
        }
        *(float4*)&Dr[r * N + m0] = make_float4(d0[0], d0[1], d0[2], d0[3]);
    }
    // ---- rows 8..15: convert acc -> d in registers (sq then dead) ----
    float dd[8][4];
#pragma unroll
    for (int r = 0; r < 8; ++r) {
        const int n = n0 + 8 + r;
#pragma unroll
        for (int j = 0; j < 4; ++j) {
            float d = sq[j] - 2.f * acc[8 + r][j];
            dd[r][j] = (m0 + j == n) ? INF : d;
        }
    }
    __syncthreads();  // Dr rows 0..7 visible
    const int w = tid >> 6, lane = tid & 63;
    const float* __restrict__ rp = &Dr[w * N];
    float v[32];
#pragma unroll
    for (int q = 0; q < 8; ++q) {
        float4 x4 = *(const float4*)&rp[lane * 4 + q * 256];
        v[q * 4 + 0] = x4.x; v[q * 4 + 1] = x4.y;
        v[q * 4 + 2] = x4.z; v[q * 4 + 3] = x4.w;
    }
    __syncthreads();  // pass-1 reads done; Dr reusable
    // ---- write rows 8..15 into Dr (dd dies here, BEFORE topk) ----
#pragma unroll
    for (int r = 0; r < 8; ++r) {
        *(float4*)&Dr[r * N + m0] = make_float4(dd[r][0], dd[r][1], dd[r][2], dd[r][3]);
    }
    topk20(v, cand + w * 64, lane, Iout, (b * N + n0 + w) * K);
    __syncthreads();  // rows 8..15 stores visible
#pragma unroll
    for (int q = 0; q < 8; ++q) {
        float4 x4 = *(const float4*)&rp[lane * 4 + q * 256];
        v[q * 4 + 0] = x4.x; v[q * 4 + 1] = x4.y;
        v[q * 4 + 2] = x4.z; v[q * 4 + 3] = x4.w;
    }
    topk20(v, cand + w * 64, lane, Iout, (b * N + n0 + 8 + w) * K);
}

// ---------------------------------------------------------------------------
// select0: layer-0 (C=3) — scores inline, register topk.
// ---------------------------------------------------------------------------
__global__ __launch_bounds__(256) void select0_kernel(const float* __restrict__ X,
                                                      int* __restrict__ Iout) {
    const int N = NPTS, K = 20;
    __shared__ unsigned long long cand[4][64];
    const int w = threadIdx.x >> 6, lane = threadIdx.x & 63;
    const int rowg = blockIdx.x * 4 + w;
    const int b = rowg >> 11, n = rowg & 2047;
    const float* __restrict__ Xb = X + (size_t)b * 3 * N;
    const float xr = Xb[n], yr = Xb[N + n], zr = Xb[2 * N + n];
    const float INF = __builtin_inff();
    float v[32];
#pragma unroll
    for (int q = 0; q < 8; ++q) {
        const int base = lane * 4 + q * 256;
        const float4 xm = *(const float4*)&Xb[base];
        const float4 ym = *(const float4*)&Xb[N + base];
        const float4 zm = *(const float4*)&Xb[2 * N + base];
        float mx[4] = {xm.x, xm.y, xm.z, xm.w};
        float my[4] = {ym.x, ym.y, ym.z, ym.w};
        float mz[4] = {zm.x, zm.y, zm.z, zm.w};
#pragma unroll
        for (int j = 0; j < 4; ++j) {
            float sq = mx[j] * mx[j] + my[j] * my[j] + mz[j] * mz[j];
            float dot = xr * mx[j] + yr * my[j] + zr * mz[j];
            float d = sq - 2.f * dot;
            v[q * 4 + j] = (base + j == n) ? INF : d;
        }
    }
    topk20(v, &cand[w][0], lane, Iout, (b * N + n) * K);
}

// ---------------------------------------------------------------------------
// U/T GEMMs (unchanged).
// ---------------------------------------------------------------------------
template<int F, int C>
__global__ __launch_bounds__(256) void ut_kernel(const float* __restrict__ X, int bs,
                                                 const float* __restrict__ W,
                                                 const float* __restrict__ bias,
                                                 float* __restrict__ U, float* __restrict__ T) {
    const int N = NPTS;
    __shared__ float Ws2[64][C + 1];
    __shared__ float Wsd[64][C + 1];
    const int n0 = blockIdx.x * 64, f0 = blockIdx.y * 64, b = blockIdx.z;
    const int tid = threadIdx.x;
    for (int i = tid; i < 64 * C; i += 256) {
        int ff = i / C, c = i - ff * C;
        float w1 = W[(f0 + ff) * (2 * C) + c];
        float w2 = W[(f0 + ff) * (2 * C) + C + c];
        Ws2[ff][c] = w2;
        Wsd[ff][c] = w1 - w2;
    }
    __syncthreads();
    const int nt = tid & 15, fg = tid >> 4;
    const float* __restrict__ Xb = X + (size_t)b * bs;
    float au[4][4], av[4][4];
#pragma unroll
    for (int i = 0; i < 4; ++i)
#pragma unroll
        for (int j = 0; j < 4; ++j) { au[i][j] = 0.f; av[i][j] = 0.f; }
#pragma unroll 4
    for (int c = 0; c < C; ++c) {
        const float4 xv = *(const float4*)&Xb[(size_t)c * N + n0 + nt * 4];
#pragma unroll
        for (int fi = 0; fi < 4; ++fi) {
            float w2v = Ws2[fg * 4 + fi][c];
            float wdv = Wsd[fg * 4 + fi][c];
            au[fi][0] += w2v * xv.x; au[fi][1] += w2v * xv.y;
            au[fi][2] += w2v * xv.z; au[fi][3] += w2v * xv.w;
            av[fi][0] += wdv * xv.x; av[fi][1] += wdv * xv.y;
            av[fi][2] += wdv * xv.z; av[fi][3] += wdv * xv.w;
        }
    }
#pragma unroll
    for (int ni = 0; ni < 4; ++ni) {
        int n = n0 + nt * 4 + ni;
        float4 uv = make_float4(au[0][ni], au[1][ni], au[2][ni], au[3][ni]);
        *(float4*)&U[((size_t)b * N + n) * F + f0 + fg * 4] = uv;
    }
#pragma unroll
    for (int fi = 0; fi < 4; ++fi) {
        int f = f0 + fg * 4 + fi;
        float bv = bias[f];
        float4 tv = make_float4(av[fi][0] + bv, av[fi][1] + bv, av[fi][2] + bv, av[fi][3] + bv);
        *(float4*)&T[((size_t)b * F + f) * N + n0 + nt * 4] = tv;
    }
}

// ---------------------------------------------------------------------------
// Gather-max: block = 32 points x 8 f-groups. Writes fp32 Hc slice (optional,
// needed as next-layer KNN input) AND bf16 hi/lo into Ht[b][n][320] at column
// offset `hoff` (c-contiguous — the MFMA A-operand layout for conv0).
// ---------------------------------------------------------------------------
template<int F, bool WRITE_F32>
__global__ __launch_bounds__(256) void gathermax_kernel(const float* __restrict__ U,
                                                        const float* __restrict__ T,
                                                        const int* __restrict__ idx,
                                                        float* __restrict__ Y, int bsY,
                                                        unsigned short* __restrict__ HtH,
                                                        unsigned short* __restrict__ HtL,
                                                        int hoff) {
    const int N = NPTS, K = 20, FG = F / 8;
    __shared__ int sidx[32 * 20];
    const int b = blockIdx.y, n0 = blockIdx.x * 32, tid = threadIdx.x;
    const int p = tid >> 3, fg = tid & 7;
    for (int t = tid; t < 32 * K; t += 256) sidx[t] = idx[(b * N + n0) * K + t];
    __syncthreads();
    const int n = n0 + p;
    const float* __restrict__ Ub = U + (size_t)b * N * F;
    const int fbase = fg * FG;
    float mx[FG];
#pragma unroll
    for (int i = 0; i < FG; ++i) mx[i] = -__builtin_inff();
#pragma unroll 4
    for (int j = 0; j < K; ++j) {
        const int r = sidx[p * K + j];
        const float4* up = (const float4*)&Ub[(size_t)r * F + fbase];
#pragma unroll
        for (int q = 0; q < FG / 4; ++q) {
            float4 a = up[q];
            mx[q * 4 + 0] = fmaxf(mx[q * 4 + 0], a.x);
            mx[q * 4 + 1] = fmaxf(mx[q * 4 + 1], a.y);
            mx[q * 4 + 2] = fmaxf(mx[q * 4 + 2], a.z);
            mx[q * 4 + 3] = fmaxf(mx[q * 4 + 3], a.w);
        }
    }
    float val[FG];
#pragma unroll
    for (int i = 0; i < FG; ++i) {
        const int f = fbase + i;
        val[i] = T[((size_t)b * F + f) * N + n] + mx[i];
        if (WRITE_F32) Y[(size_t)b * bsY + (size_t)f * N + n] = val[i];
    }
    // bf16 hi/lo split, c-contiguous at Ht[b][n][hoff + fbase ...]
    unsigned short hs[FG], ls[FG];
#pragma unroll
    for (int i = 0; i < FG; ++i) {
        unsigned short h = f2bf(val[i]);
        hs[i] = h;
        ls[i] = f2bf(val[i] - bf2f(h));
    }
    const size_t hb = ((size_t)b * N + n) * 320 + hoff + fbase;
#pragma unroll
    for (int q = 0; q < FG / 8; ++q) {
        *(int4*)&HtH[hb + q * 8] = *(const int4*)&hs[q * 8];
        *(int4*)&HtL[hb + q * 8] = *(const int4*)&ls[q * 8];
    }
}

// ---------------------------------------------------------------------------
// conv0_w -> bf16 hi/lo split (one-shot, 1024x320 elements).
// ---------------------------------------------------------------------------
__global__ __launch_bounds__(256) void wsplit_kernel(const float* __restrict__ W,
                                                     unsigned short* __restrict__ WH,
                                                     unsigned short* __restrict__ WL) {
    const int e = blockIdx.x * 256 + threadIdx.x;
    float w = W[e];
    unsigned short h = f2bf(w);
    WH[e] = h;
    WL[e] = f2bf(w - bf2f(h));
}

// ---------------------------------------------------------------------------
// conv0 + global max via bf16x3 MFMA emulation:
//   W.H ~= Whi.Hhi + Whi.Hlo + Wlo.Hhi  (error ~2^-18 rel per term).
// Block tile: 64 n x 128 f; per wave 32n x 64f = 2x4 16x16x32 tiles, 3 MFMA
// each per 32-c chunk. LDS rows padded to 40 shorts: b128 frag reads spread
// uniformly over all 8 bank-quads (conflict-free).
// ---------------------------------------------------------------------------
__global__ __launch_bounds__(256) void conv0mfma_kernel(const unsigned short* __restrict__ HtH,
                                                        const unsigned short* __restrict__ HtL,
                                                        const unsigned short* __restrict__ WH,
                                                        const unsigned short* __restrict__ WL,
                                                        unsigned* __restrict__ M) {
    const int N = NPTS;
    __shared__ unsigned short HsH[64][40], HsL[64][40], WsH[128][40], WsL[128][40];
    const int n0 = blockIdx.x * 64, f0 = blockIdx.y * 128, b = blockIdx.z;
    const int tid = threadIdx.x;
    const int wave = tid >> 6, lane = tid & 63;
    const int wm = wave & 1, wf = wave >> 1;
    const int row = lane & 15, quad = lane >> 4;
    f32x4 acc[2][4];
#pragma unroll
    for (int i = 0; i < 2; ++i)
#pragma unroll
        for (int j = 0; j < 4; ++j) acc[i][j] = (f32x4){0.f, 0.f, 0.f, 0.f};

    const int hn = tid >> 2, hq = tid & 3;   // H staging: 64 rows x 4 chunks
    const int wfr = tid >> 1, wq = tid & 1;  // W staging: 128 rows x 2 chunks

    for (int c0 = 0; c0 < 320; c0 += 32) {
        {
            const size_t src = ((size_t)b * N + n0 + hn) * 320 + c0 + hq * 8;
            *(int4*)&HsH[hn][hq * 8] = *(const int4*)&HtH[src];
            *(int4*)&HsL[hn][hq * 8] = *(const int4*)&HtL[src];
        }
        {
            const size_t src = (size_t)(f0 + wfr) * 320 + c0 + wq * 16;
            *(int4*)&WsH[wfr][wq * 16]     = *(const int4*)&WH[src];
            *(int4*)&WsH[wfr][wq * 16 + 8] = *(const int4*)&WH[src + 8];
            *(int4*)&WsL[wfr][wq * 16]     = *(const int4*)&WL[src];
            *(int4*)&WsL[wfr][wq * 16 + 8] = *(const int4*)&WL[src + 8];
        }
        __syncthreads();
        bf16x8 aH[2], aL[2];
#pragma unroll
        for (int mt = 0; mt < 2; ++mt) {
            aH[mt] = *(const bf16x8*)&HsH[wm * 32 + mt * 16 + row][quad * 8];
            aL[mt] = *(const bf16x8*)&HsL[wm * 32 + mt * 16 + row][quad * 8];
        }
#pragma unroll
        for (int nt = 0; nt < 4; ++nt) {
            bf16x8 bH = *(const bf16x8*)&WsH[wf * 64 + nt * 16 + row][quad * 8];
            bf16x8 bL = *(const bf16x8*)&WsL[wf * 64 + nt * 16 + row][quad * 8];
#pragma unroll
            for (int mt = 0; mt < 2; ++mt) {
                acc[mt][nt] = __builtin_amdgcn_mfma_f32_16x16x32_bf16(aH[mt], bH, acc[mt][nt], 0, 0, 0);
                acc[mt][nt] = __builtin_amdgcn_mfma_f32_16x16x32_bf16(aH[mt], bL, acc[mt][nt], 0, 0, 0);
                acc[mt][nt] = __builtin_amdgcn_mfma_f32_16x16x32_bf16(aL[mt], bH, acc[mt][nt], 0, 0, 0);
            }
        }
        __syncthreads();
    }
    // D[m=n_pt][col=f]: col = lane&15, row = quad*4 + reg. Max over this
    // wave's 32 n: lane-local (2 mt x 4 regs), then across quads (shfl 16,32).
#pragma unroll
    for (int nt = 0; nt < 4; ++nt) {
        float m = acc[0][nt][0];
#pragma unroll
        for (int r = 1; r < 4; ++r) m = fmaxf(m, acc[0][nt][r]);
#pragma unroll
        for (int r = 0; r < 4; ++r) m = fmaxf(m, acc[1][nt][r]);
        m = fmaxf(m, __shfl_down(m, 16));
        m = fmaxf(m, __shfl_down(m, 32));
        if (quad == 0)
            atomicMax(&M[(b << 10) + f0 + wf * 64 + nt * 16 + row], fenc(m));
    }
}

// ---------------------------------------------------------------------------
// Fused head (unchanged).
// ---------------------------------------------------------------------------
__global__ __launch_bounds__(256) void fc_kernel(const unsigned* __restrict__ M,
    const float* __restrict__ cb, const float* __restrict__ cs, const float* __restrict__ ct,
    const float* __restrict__ w0, const float* __restrict__ b0, const float* __restrict__ s0, const float* __restrict__ t0,
    const float* __restrict__ w1, const float* __restrict__ b1, const float* __restrict__ s1, const float* __restrict__ t1,
    const float* __restrict__ w2, const float* __restrict__ b2, const float* __restrict__ s2, const float* __restrict__ t2,
    float* __restrict__ out) {
    __shared__ float g0[1024], g1[512], g2[256];
    const int b = blockIdx.x, tid = threadIdx.x;
    for (int f = tid; f < 1024; f += 256) {
        float z = fdec(M[b * 1024 + f]);
        float g = cs[f] * (z + cb[f]) + ct[f];
        g0[f] = fmaxf(g, 0.f);
    }
    __syncthreads();
    for (int f = tid; f < 512; f += 256) {
        const float4* wp = (const float4*)(w0 + (size_t)f * 1024);
        float acc = 0.f;
#pragma unroll 4
        for (int c = 0; c < 256; ++c) {
            float4 wv = wp[c];
            float4 gv = *(const float4*)&g0[c * 4];
            acc += wv.x * gv.x + wv.y * gv.y + wv.z * gv.z + wv.w * gv.w;
        }
        float g = s0[f] * (acc + b0[f]) + t0[f];
        g1[f] = fmaxf(g, 0.f);
    }
    __syncthreads();
    if (tid < 256) {
        const float4* wp = (const float4*)(w1 + (size_t)tid * 512);
        float acc = 0.f;
#pragma unroll 4
        for (int c = 0; c < 128; ++c) {
            float4 wv = wp[c];
            float4 gv = *(const float4*)&g1[c * 4];
            acc += wv.x * gv.x + wv.y * gv.y + wv.z * gv.z + wv.w * gv.w;
        }
        float g = s1[tid] * (acc + b1[tid]) + t1[tid];
        g2[tid] = fmaxf(g, 0.f);
    }
    __syncthreads();
    if (tid < 40) {
        const float4* wp = (const float4*)(w2 + (size_t)tid * 256);
        float acc = 0.f;
#pragma unroll 4
        for (int c = 0; c < 64; ++c) {
            float4 wv = wp[c];
            float4 gv = *(const float4*)&g2[c * 4];
            acc += wv.x * gv.x + wv.y * gv.y + wv.z * gv.z + wv.w * gv.w;
        }
        float g = s2[tid] * (acc + b2[tid]) + t2[tid];
        out[b * 40 + tid] = fmaxf(g, 0.f);
    }
}

// ---------------------------------------------------------------------------
extern "C" void kernel_launch(void* const* d_in, const int* in_sizes, int n_in,
                              void* d_out, int out_size, void* d_ws, size_t ws_size,
                              hipStream_t stream) {
    const float* x       = (const float*)d_in[0];
    const float* ec0_w   = (const float*)d_in[1];
    const float* ec0_b   = (const float*)d_in[2];
    const float* ec1_w   = (const float*)d_in[3];
    const float* ec1_b   = (const float*)d_in[4];
    const float* ec2_w   = (const float*)d_in[5];
    const float* ec2_b   = (const float*)d_in[6];
    const float* ec3_w   = (const float*)d_in[7];
    const float* ec3_b   = (const float*)d_in[8];
    const float* conv0_w = (const float*)d_in[9];
    const float* conv0_b = (const float*)d_in[10];
    const float* conv0_s = (const float*)d_in[11];
    const float* conv0_t = (const float*)d_in[12];
    const float* fc0_w   = (const float*)d_in[13];
    const float* fc0_b   = (const float*)d_in[14];
    const float* fc0_s   = (const float*)d_in[15];
    const float* fc0_t   = (const float*)d_in[16];
    const float* fc1_w   = (const float*)d_in[17];
    const float* fc1_b   = (const float*)d_in[18];
    const float* fc1_s   = (const float*)d_in[19];
    const float* fc1_t   = (const float*)d_in[20];
    const float* fc2_w   = (const float*)d_in[21];
    const float* fc2_b   = (const float*)d_in[22];
    const float* fc2_s   = (const float*)d_in[23];
    const float* fc2_t   = (const float*)d_in[24];
    float* out = (float*)d_out;

    char* ws = (char*)d_ws;
    const int B = 16, N = NPTS;
    float* Hc   = (float*)(ws + 0);            // [16][320][2048]  41,943,040 B
    float* U    = (float*)(ws + 41943040);     // [16][2048][128]  16,777,216 B
    float* T    = (float*)(ws + 58720256);     // [16][128][2048]  16,777,216 B
    int*   I    = (int*)  (ws + 75497472);     // [16][2048][20]    2,621,440 B
    unsigned* M = (unsigned*)(ws + 78118912);  // [16][1024]           65,536 B
    unsigned short* W_hi = (unsigned short*)(ws + 78184448);  //  655,360 B
    unsigned short* W_lo = (unsigned short*)(ws + 78839808);  //  655,360 B
    unsigned short* HtH  = (unsigned short*)(ws + 79495168);  // [16][2048][320] 20,971,520 B
    unsigned short* HtL  = (unsigned short*)(ws + 100466688); // [16][2048][320] 20,971,520 B
    // end: 121,438,208 B

    (void)hipFuncSetAttribute((const void*)knnfused_kernel,
                              hipFuncAttributeMaxDynamicSharedMemorySize, 73728);

    dim3 blk(256);
    const int bsX0 = 3 * N, bsH = 320 * N;

    wsplit_kernel<<<dim3(1024 * 320 / 256), blk, 0, stream>>>(conv0_w, W_hi, W_lo);

    // ---- Layer 0 (C=3 -> F=64) ----
    select0_kernel<<<dim3(B * N / 4), blk, 0, stream>>>(x, I);
    ut_kernel<64, 3><<<dim3(N / 64, 1, B), blk, 0, stream>>>(x, bsX0, ec0_w, ec0_b, U, T);
    gathermax_kernel<64, true><<<dim3(N / 32, B), blk, 0, stream>>>(U, T, I, Hc, bsH, HtH, HtL, 0);

    // ---- Layers 1..3 (C=64): fused dist+select with inline sq ----
    const float* Xin[3] = {Hc, Hc + (size_t)64 * N, Hc + (size_t)128 * N};
    const float* ecw[3] = {ec1_w, ec2_w, ec3_w};
    const float* ecb[3] = {ec1_b, ec2_b, ec3_b};
    for (int L = 0; L < 3; ++L) {
        knnfused_kernel<<<dim3(N / 16, B), dim3(512), 73728, stream>>>(Xin[L], bsH, I);
        if (L < 2) {
            ut_kernel<64, 64><<<dim3(N / 64, 1, B), blk, 0, stream>>>(Xin[L], bsH, ecw[L], ecb[L], U, T);
            gathermax_kernel<64, true><<<dim3(N / 32, B), blk, 0, stream>>>(
                U, T, I, Hc + (size_t)(64 * (L + 1)) * N, bsH, HtH, HtL, 64 * (L + 1));
        } else {
            ut_kernel<128, 64><<<dim3(N / 64, 2, B), blk, 0, stream>>>(Xin[L], bsH, ecw[L], ecb[L], U, T);
            gathermax_kernel<128, false><<<dim3(N / 32, B), blk, 0, stream>>>(
                U, T, I, Hc + (size_t)192 * N, bsH, HtH, HtL, 192);
        }
    }

    // ---- conv0 + global max (bf16x3 MFMA) ----
    (void)hipMemsetAsync(M, 0, B * 1024 * sizeof(unsigned), stream);
    conv0mfma_kernel<<<dim3(N / 64, 1024 / 128, B), blk, 0, stream>>>(HtH, HtL, W_hi, W_lo, M);

    // ---- head ----
    fc_kernel<<<dim3(B), blk, 0, stream>>>(M, conv0_b, conv0_s, conv0_t,
                                           fc0_w, fc0_b, fc0_s, fc0_t,
                                           fc1_w, fc1_b, fc1_s, fc1_t,
                                           fc2_w, fc2_b, fc2_s, fc2_t, out);
}

// Round 5
// 951.162 us; speedup vs baseline: 1.2847x; 1.0166x over previous
//
#include <hip/hip_runtime.h>

#define DEVINL __device__ __forceinline__

static const int NPTS = 2048;

typedef __attribute__((ext_vector_type(8))) short bf16x8;
typedef __attribute__((ext_vector_type(4))) float f32x4;

DEVINL unsigned fenc(float x) {
    int b = __float_as_int(x);
    return (b < 0) ? ~(unsigned)b : ((unsigned)b | 0x80000000u);
}
DEVINL float fdec(unsigned u) {
    return (u & 0x80000000u) ? __int_as_float((int)(u & 0x7fffffffu))
                             : __int_as_float((int)~u);
}
DEVINL unsigned long long u64min(unsigned long long a, unsigned long long b) {
    return (b < a) ? b : a;
}
DEVINL unsigned short f2bf(float x) {  // round-to-nearest-even bf16 (finite inputs)
    unsigned u = __float_as_uint(x);
    return (unsigned short)((u + 0x7fffu + ((u >> 16) & 1u)) >> 16);
}
DEVINL float bf2f(unsigned short h) { return __uint_as_float(((unsigned)h) << 16); }

// ---------------------------------------------------------------------------
// Exact top-20 of a row held as v[32] per lane (col(j) = lane*4+(j&3)+(j>>2)*256).
// tau = 20th smallest of the 64 lane-minima; ballot-compact <=tau (E~25) ->
// u64 bitonic sort -> lanes 0..19. Fallback (>64 cands, ~never): low-register
// 20-round lexicographic (fenc(v), col) tournament with a taken-bitmask —
// identical ordering to a u64 (fenc<<32)|col key but ~8 extra VGPRs not 64.
// ---------------------------------------------------------------------------
DEVINL void topk20(float v[32], unsigned long long* cand, int lane,
                   int* __restrict__ Iout, int outBase) {
    float t16[16];
#pragma unroll
    for (int i = 0; i < 16; ++i) t16[i] = fminf(v[i], v[i + 16]);
#pragma unroll
    for (int i = 0; i < 8; ++i) t16[i] = fminf(t16[i], t16[i + 8]);
#pragma unroll
    for (int i = 0; i < 4; ++i) t16[i] = fminf(t16[i], t16[i + 4]);
    float s = fminf(fminf(t16[0], t16[1]), fminf(t16[2], t16[3]));
#pragma unroll
    for (int k = 2; k <= 64; k <<= 1) {
#pragma unroll
        for (int j = k >> 1; j >= 1; j >>= 1) {
            float o = __shfl_xor(s, j);
            bool keepmin = (((lane & j) == 0) == ((lane & k) == 0));
            s = keepmin ? fminf(s, o) : fmaxf(s, o);
        }
    }
    const float tau = __shfl(s, 19);
    int cnt = 0;
#pragma unroll
    for (int j = 0; j < 32; ++j) {
        bool pass = (v[j] <= tau);
        unsigned long long mask = __ballot(pass);
        if (pass) {
            int pos = cnt + (int)__popcll(mask & ((1ull << lane) - 1ull));
            if (pos < 64) {
                int col = lane * 4 + (j & 3) + ((j >> 2) << 8);
                cand[pos] = ((unsigned long long)fenc(v[j]) << 32) | (unsigned)col;
            }
        }
        cnt += (int)__popcll(mask);
    }
    if (cnt <= 64) {
        unsigned long long key = (lane < cnt) ? cand[lane] : ~0ull;
#pragma unroll
        for (int k = 2; k <= 64; k <<= 1) {
#pragma unroll
            for (int j = k >> 1; j >= 1; j >>= 1) {
                unsigned long long o = __shfl_xor(key, j);
                bool keepmin = (((lane & j) == 0) == ((lane & k) == 0));
                unsigned long long mn = u64min(key, o);
                unsigned long long mx = (key ^ o) ^ mn;
                key = keepmin ? mn : mx;
            }
        }
        if (lane < 20) Iout[outBase + lane] = (int)(unsigned)(key & 0xffffffffu);
    } else {
        // Cold exact path: 20 rounds of global lex-min over (fenc(v), col).
        unsigned vu[32];
#pragma unroll
        for (int j = 0; j < 32; ++j) vu[j] = fenc(v[j]);
        unsigned taken = 0u;
        for (int it = 0; it < 20; ++it) {
            unsigned bk = 0xffffffffu;
            int bc = 0x7fffffff, bj = 0;
#pragma unroll
            for (int j = 0; j < 32; ++j) {
                const int col = lane * 4 + (j & 3) + ((j >> 2) << 8);
                bool avail = ((taken >> j) & 1u) == 0u;
                bool better = avail && (vu[j] < bk || (vu[j] == bk && col < bc));
                bk = better ? vu[j] : bk;
                bc = better ? col : bc;
                bj = better ? j : bj;
            }
            const int lbc = bc;  // lane-local winner col (unique across lanes)
#pragma unroll
            for (int off = 32; off >= 1; off >>= 1) {
                unsigned ok = __shfl_xor(bk, off);
                int oc = __shfl_xor(bc, off);
                bool t = (ok < bk) || (ok == bk && oc < bc);
                bk = t ? ok : bk;
                bc = t ? oc : bc;
            }
            if (lane == 0) Iout[outBase + it] = bc;
            if (lbc == bc) taken |= (1u << bj);
        }
    }
}

// ---------------------------------------------------------------------------
// Fused KNN (C=64) with inline sq: block owns 16 rows; GEMM 16x2048x64 with A
// in LDS, B streamed (16-row reuse halves streamed-B L2 traffic vs 8-row).
// rd3 lesson: launch_bounds(512,4) gave the allocator a 64-reg budget ->
// ~6 regs/thread spilled to scratch (WRITE_SIZE 25.5MB). LDS (72KB) caps
// residency at 2 blocks/CU anyway, so (512,2) raises the reg cap to >=128
// with zero occupancy loss. c-loop unroll 2 + A-fragment loads adjacent to
// their 8-row FMA group to halve pipelined temps. Per-element FMA chains keep
// ascending-c order -> bit-identical distances. Topk in 2 passes over
// Dr[8][2048]; rows 8-15 written to Dr BEFORE the first topk (no registers
// live across topk).
// ---------------------------------------------------------------------------
__global__ __launch_bounds__(512, 2) void knnfused_kernel(const float* __restrict__ X, int bs,
                                                          int* __restrict__ Iout) {
    extern __shared__ char smem[];
    float* Dr = (float*)smem;                                       // [8][2048] 64 KB
    float* As = (float*)(smem + 65536);                             // [64][16]   4 KB
    unsigned long long* cand = (unsigned long long*)(smem + 69632); // [8][64]    4 KB
    const int N = NPTS, K = 20;
    const int b = blockIdx.y, n0 = blockIdx.x * 16;
    const float* __restrict__ Xb = X + (size_t)b * bs;
    const int tid = threadIdx.x;
    if (tid < 256) {
        int c = tid >> 2, r4 = (tid & 3) * 4;
        *(float4*)&As[c * 16 + r4] = *(const float4*)&Xb[(size_t)c * N + n0 + r4];
    }
    __syncthreads();
    const int m0 = tid * 4;
    float acc[16][4], sq[4];
#pragma unroll
    for (int r = 0; r < 16; ++r)
#pragma unroll
        for (int j = 0; j < 4; ++j) acc[r][j] = 0.f;
#pragma unroll
    for (int j = 0; j < 4; ++j) sq[j] = 0.f;
#pragma unroll 2
    for (int c = 0; c < 64; ++c) {
        float4 b0 = *(const float4*)&Xb[(size_t)c * N + m0];
        sq[0] += b0.x * b0.x; sq[1] += b0.y * b0.y;
        sq[2] += b0.z * b0.z; sq[3] += b0.w * b0.w;
        {
            float4 a0 = *(const float4*)&As[c * 16];
            float4 a1 = *(const float4*)&As[c * 16 + 4];
            float av[8] = {a0.x, a0.y, a0.z, a0.w, a1.x, a1.y, a1.z, a1.w};
#pragma unroll
            for (int r = 0; r < 8; ++r) {
                acc[r][0] += av[r] * b0.x; acc[r][1] += av[r] * b0.y;
                acc[r][2] += av[r] * b0.z; acc[r][3] += av[r] * b0.w;
            }
        }
        {
            float4 a2 = *(const float4*)&As[c * 16 + 8];
            float4 a3 = *(const float4*)&As[c * 16 + 12];
            float aw[8] = {a2.x, a2.y, a2.z, a2.w, a3.x, a3.y, a3.z, a3.w};
#pragma unroll
            for (int r = 0; r < 8; ++r) {
                acc[8 + r][0] += aw[r] * b0.x; acc[8 + r][1] += aw[r] * b0.y;
                acc[8 + r][2] += aw[r] * b0.z; acc[8 + r][3] += aw[r] * b0.w;
            }
        }
    }
    const float INF = __builtin_inff();
    // ---- rows 0..7: d -> Dr ----
#pragma unroll
    for (int r = 0; r < 8; ++r) {
        const int n = n0 + r;
        float d0[4] = {sq[0] - 2.f * acc[r][0], sq[1] - 2.f * acc[r][1],
                       sq[2] - 2.f * acc[r][2], sq[3] - 2.f * acc[r][3]};
#pragma unroll
        for (int j = 0; j < 4; ++j) {
            if (m0 + j == n) d0[j] = INF;
        }
        *(float4*)&Dr[r * N + m0] = make_float4(d0[0], d0[1], d0[2], d0[3]);
    }
    // ---- rows 8..15: convert acc -> d in registers (sq then dead) ----
    float dd[8][4];
#pragma unroll
    for (int r = 0; r < 8; ++r) {
        const int n = n0 + 8 + r;
#pragma unroll
        for (int j = 0; j < 4; ++j) {
            float d = sq[j] - 2.f * acc[8 + r][j];
            dd[r][j] = (m0 + j == n) ? INF : d;
        }
    }
    __syncthreads();  // Dr rows 0..7 visible
    const int w = tid >> 6, lane = tid & 63;
    const float* __restrict__ rp = &Dr[w * N];
    float v[32];
#pragma unroll
    for (int q = 0; q < 8; ++q) {
        float4 x4 = *(const float4*)&rp[lane * 4 + q * 256];
        v[q * 4 + 0] = x4.x; v[q * 4 + 1] = x4.y;
        v[q * 4 + 2] = x4.z; v[q * 4 + 3] = x4.w;
    }
    __syncthreads();  // pass-1 reads done; Dr reusable
    // ---- write rows 8..15 into Dr (dd dies here, BEFORE topk) ----
#pragma unroll
    for (int r = 0; r < 8; ++r) {
        *(float4*)&Dr[r * N + m0] = make_float4(dd[r][0], dd[r][1], dd[r][2], dd[r][3]);
    }
    topk20(v, cand + w * 64, lane, Iout, (b * N + n0 + w) * K);
    __syncthreads();  // rows 8..15 stores visible
#pragma unroll
    for (int q = 0; q < 8; ++q) {
        float4 x4 = *(const float4*)&rp[lane * 4 + q * 256];
        v[q * 4 + 0] = x4.x; v[q * 4 + 1] = x4.y;
        v[q * 4 + 2] = x4.z; v[q * 4 + 3] = x4.w;
    }
    topk20(v, cand + w * 64, lane, Iout, (b * N + n0 + 8 + w) * K);
}

// ---------------------------------------------------------------------------
// select0: layer-0 (C=3) — scores inline, register topk.
// ---------------------------------------------------------------------------
__global__ __launch_bounds__(256) void select0_kernel(const float* __restrict__ X,
                                                      int* __restrict__ Iout) {
    const int N = NPTS, K = 20;
    __shared__ unsigned long long cand[4][64];
    const int w = threadIdx.x >> 6, lane = threadIdx.x & 63;
    const int rowg = blockIdx.x * 4 + w;
    const int b = rowg >> 11, n = rowg & 2047;
    const float* __restrict__ Xb = X + (size_t)b * 3 * N;
    const float xr = Xb[n], yr = Xb[N + n], zr = Xb[2 * N + n];
    const float INF = __builtin_inff();
    float v[32];
#pragma unroll
    for (int q = 0; q < 8; ++q) {
        const int base = lane * 4 + q * 256;
        const float4 xm = *(const float4*)&Xb[base];
        const float4 ym = *(const float4*)&Xb[N + base];
        const float4 zm = *(const float4*)&Xb[2 * N + base];
        float mx[4] = {xm.x, xm.y, xm.z, xm.w};
        float my[4] = {ym.x, ym.y, ym.z, ym.w};
        float mz[4] = {zm.x, zm.y, zm.z, zm.w};
#pragma unroll
        for (int j = 0; j < 4; ++j) {
            float sq = mx[j] * mx[j] + my[j] * my[j] + mz[j] * mz[j];
            float dot = xr * mx[j] + yr * my[j] + zr * mz[j];
            float d = sq - 2.f * dot;
            v[q * 4 + j] = (base + j == n) ? INF : d;
        }
    }
    topk20(v, &cand[w][0], lane, Iout, (b * N + n) * K);
}

// ---------------------------------------------------------------------------
// U/T GEMMs (unchanged).
// ---------------------------------------------------------------------------
template<int F, int C>
__global__ __launch_bounds__(256) void ut_kernel(const float* __restrict__ X, int bs,
                                                 const float* __restrict__ W,
                                                 const float* __restrict__ bias,
                                                 float* __restrict__ U, float* __restrict__ T) {
    const int N = NPTS;
    __shared__ float Ws2[64][C + 1];
    __shared__ float Wsd[64][C + 1];
    const int n0 = blockIdx.x * 64, f0 = blockIdx.y * 64, b = blockIdx.z;
    const int tid = threadIdx.x;
    for (int i = tid; i < 64 * C; i += 256) {
        int ff = i / C, c = i - ff * C;
        float w1 = W[(f0 + ff) * (2 * C) + c];
        float w2 = W[(f0 + ff) * (2 * C) + C + c];
        Ws2[ff][c] = w2;
        Wsd[ff][c] = w1 - w2;
    }
    __syncthreads();
    const int nt = tid & 15, fg = tid >> 4;
    const float* __restrict__ Xb = X + (size_t)b * bs;
    float au[4][4], av[4][4];
#pragma unroll
    for (int i = 0; i < 4; ++i)
#pragma unroll
        for (int j = 0; j < 4; ++j) { au[i][j] = 0.f; av[i][j] = 0.f; }
#pragma unroll 4
    for (int c = 0; c < C; ++c) {
        const float4 xv = *(const float4*)&Xb[(size_t)c * N + n0 + nt * 4];
#pragma unroll
        for (int fi = 0; fi < 4; ++fi) {
            float w2v = Ws2[fg * 4 + fi][c];
            float wdv = Wsd[fg * 4 + fi][c];
            au[fi][0] += w2v * xv.x; au[fi][1] += w2v * xv.y;
            au[fi][2] += w2v * xv.z; au[fi][3] += w2v * xv.w;
            av[fi][0] += wdv * xv.x; av[fi][1] += wdv * xv.y;
            av[fi][2] += wdv * xv.z; av[fi][3] += wdv * xv.w;
        }
    }
#pragma unroll
    for (int ni = 0; ni < 4; ++ni) {
        int n = n0 + nt * 4 + ni;
        float4 uv = make_float4(au[0][ni], au[1][ni], au[2][ni], au[3][ni]);
        *(float4*)&U[((size_t)b * N + n) * F + f0 + fg * 4] = uv;
    }
#pragma unroll
    for (int fi = 0; fi < 4; ++fi) {
        int f = f0 + fg * 4 + fi;
        float bv = bias[f];
        float4 tv = make_float4(av[fi][0] + bv, av[fi][1] + bv, av[fi][2] + bv, av[fi][3] + bv);
        *(float4*)&T[((size_t)b * F + f) * N + n0 + nt * 4] = tv;
    }
}

// ---------------------------------------------------------------------------
// Gather-max: block = 32 points x 8 f-groups. Writes fp32 Hc slice (optional,
// needed as next-layer KNN input) AND bf16 hi/lo into Ht[b][n][320] at column
// offset `hoff` (c-contiguous — the MFMA A-operand layout for conv0).
// ---------------------------------------------------------------------------
template<int F, bool WRITE_F32>
__global__ __launch_bounds__(256) void gathermax_kernel(const float* __restrict__ U,
                                                        const float* __restrict__ T,
                                                        const int* __restrict__ idx,
                                                        float* __restrict__ Y, int bsY,
                                                        unsigned short* __restrict__ HtH,
                                                        unsigned short* __restrict__ HtL,
                                                        int hoff) {
    const int N = NPTS, K = 20, FG = F / 8;
    __shared__ int sidx[32 * 20];
    const int b = blockIdx.y, n0 = blockIdx.x * 32, tid = threadIdx.x;
    const int p = tid >> 3, fg = tid & 7;
    for (int t = tid; t < 32 * K; t += 256) sidx[t] = idx[(b * N + n0) * K + t];
    __syncthreads();
    const int n = n0 + p;
    const float* __restrict__ Ub = U + (size_t)b * N * F;
    const int fbase = fg * FG;
    float mx[FG];
#pragma unroll
    for (int i = 0; i < FG; ++i) mx[i] = -__builtin_inff();
#pragma unroll 4
    for (int j = 0; j < K; ++j) {
        const int r = sidx[p * K + j];
        const float4* up = (const float4*)&Ub[(size_t)r * F + fbase];
#pragma unroll
        for (int q = 0; q < FG / 4; ++q) {
            float4 a = up[q];
            mx[q * 4 + 0] = fmaxf(mx[q * 4 + 0], a.x);
            mx[q * 4 + 1] = fmaxf(mx[q * 4 + 1], a.y);
            mx[q * 4 + 2] = fmaxf(mx[q * 4 + 2], a.z);
            mx[q * 4 + 3] = fmaxf(mx[q * 4 + 3], a.w);
        }
    }
    float val[FG];
#pragma unroll
    for (int i = 0; i < FG; ++i) {
        const int f = fbase + i;
        val[i] = T[((size_t)b * F + f) * N + n] + mx[i];
        if (WRITE_F32) Y[(size_t)b * bsY + (size_t)f * N + n] = val[i];
    }
    // bf16 hi/lo split, c-contiguous at Ht[b][n][hoff + fbase ...]
    unsigned short hs[FG], ls[FG];
#pragma unroll
    for (int i = 0; i < FG; ++i) {
        unsigned short h = f2bf(val[i]);
        hs[i] = h;
        ls[i] = f2bf(val[i] - bf2f(h));
    }
    const size_t hb = ((size_t)b * N + n) * 320 + hoff + fbase;
#pragma unroll
    for (int q = 0; q < FG / 8; ++q) {
        *(int4*)&HtH[hb + q * 8] = *(const int4*)&hs[q * 8];
        *(int4*)&HtL[hb + q * 8] = *(const int4*)&ls[q * 8];
    }
}

// ---------------------------------------------------------------------------
// conv0_w -> bf16 hi/lo split (one-shot, 1024x320 elements).
// ---------------------------------------------------------------------------
__global__ __launch_bounds__(256) void wsplit_kernel(const float* __restrict__ W,
                                                     unsigned short* __restrict__ WH,
                                                     unsigned short* __restrict__ WL) {
    const int e = blockIdx.x * 256 + threadIdx.x;
    float w = W[e];
    unsigned short h = f2bf(w);
    WH[e] = h;
    WL[e] = f2bf(w - bf2f(h));
}

// ---------------------------------------------------------------------------
// conv0 + global max via bf16x3 MFMA emulation:
//   W.H ~= Whi.Hhi + Whi.Hlo + Wlo.Hhi  (error ~2^-18 rel per term).
// Block tile: 64 n x 128 f; per wave 32n x 64f = 2x4 16x16x32 tiles, 3 MFMA
// each per 32-c chunk. LDS rows padded to 40 shorts: b128 frag reads spread
// uniformly over all 8 bank-quads (conflict-free).
// ---------------------------------------------------------------------------
__global__ __launch_bounds__(256) void conv0mfma_kernel(const unsigned short* __restrict__ HtH,
                                                        const unsigned short* __restrict__ HtL,
                                                        const unsigned short* __restrict__ WH,
                                                        const unsigned short* __restrict__ WL,
                                                        unsigned* __restrict__ M) {
    const int N = NPTS;
    __shared__ unsigned short HsH[64][40], HsL[64][40], WsH[128][40], WsL[128][40];
    const int n0 = blockIdx.x * 64, f0 = blockIdx.y * 128, b = blockIdx.z;
    const int tid = threadIdx.x;
    const int wave = tid >> 6, lane = tid & 63;
    const int wm = wave & 1, wf = wave >> 1;
    const int row = lane & 15, quad = lane >> 4;
    f32x4 acc[2][4];
#pragma unroll
    for (int i = 0; i < 2; ++i)
#pragma unroll
        for (int j = 0; j < 4; ++j) acc[i][j] = (f32x4){0.f, 0.f, 0.f, 0.f};

    const int hn = tid >> 2, hq = tid & 3;   // H staging: 64 rows x 4 chunks
    const int wfr = tid >> 1, wq = tid & 1;  // W staging: 128 rows x 2 chunks

    for (int c0 = 0; c0 < 320; c0 += 32) {
        {
            const size_t src = ((size_t)b * N + n0 + hn) * 320 + c0 + hq * 8;
            *(int4*)&HsH[hn][hq * 8] = *(const int4*)&HtH[src];
            *(int4*)&HsL[hn][hq * 8] = *(const int4*)&HtL[src];
        }
        {
            const size_t src = (size_t)(f0 + wfr) * 320 + c0 + wq * 16;
            *(int4*)&WsH[wfr][wq * 16]     = *(const int4*)&WH[src];
            *(int4*)&WsH[wfr][wq * 16 + 8] = *(const int4*)&WH[src + 8];
            *(int4*)&WsL[wfr][wq * 16]     = *(const int4*)&WL[src];
            *(int4*)&WsL[wfr][wq * 16 + 8] = *(const int4*)&WL[src + 8];
        }
        __syncthreads();
        bf16x8 aH[2], aL[2];
#pragma unroll
        for (int mt = 0; mt < 2; ++mt) {
            aH[mt] = *(const bf16x8*)&HsH[wm * 32 + mt * 16 + row][quad * 8];
            aL[mt] = *(const bf16x8*)&HsL[wm * 32 + mt * 16 + row][quad * 8];
        }
#pragma unroll
        for (int nt = 0; nt < 4; ++nt) {
            bf16x8 bH = *(const bf16x8*)&WsH[wf * 64 + nt * 16 + row][quad * 8];
            bf16x8 bL = *(const bf16x8*)&WsL[wf * 64 + nt * 16 + row][quad * 8];
#pragma unroll
            for (int mt = 0; mt < 2; ++mt) {
                acc[mt][nt] = __builtin_amdgcn_mfma_f32_16x16x32_bf16(aH[mt], bH, acc[mt][nt], 0, 0, 0);
                acc[mt][nt] = __builtin_amdgcn_mfma_f32_16x16x32_bf16(aH[mt], bL, acc[mt][nt], 0, 0, 0);
                acc[mt][nt] = __builtin_amdgcn_mfma_f32_16x16x32_bf16(aL[mt], bH, acc[mt][nt], 0, 0, 0);
            }
        }
        __syncthreads();
    }
    // D[m=n_pt][col=f]: col = lane&15, row = quad*4 + reg. Max over this
    // wave's 32 n: lane-local (2 mt x 4 regs), then across quads (shfl 16,32).
#pragma unroll
    for (int nt = 0; nt < 4; ++nt) {
        float m = acc[0][nt][0];
#pragma unroll
        for (int r = 1; r < 4; ++r) m = fmaxf(m, acc[0][nt][r]);
#pragma unroll
        for (int r = 0; r < 4; ++r) m = fmaxf(m, acc[1][nt][r]);
        m = fmaxf(m, __shfl_down(m, 16));
        m = fmaxf(m, __shfl_down(m, 32));
        if (quad == 0)
            atomicMax(&M[(b << 10) + f0 + wf * 64 + nt * 16 + row], fenc(m));
    }
}

// ---------------------------------------------------------------------------
// Fused head (unchanged).
// ---------------------------------------------------------------------------
__global__ __launch_bounds__(256) void fc_kernel(const unsigned* __restrict__ M,
    const float* __restrict__ cb, const float* __restrict__ cs, const float* __restrict__ ct,
    const float* __restrict__ w0, const float* __restrict__ b0, const float* __restrict__ s0, const float* __restrict__ t0,
    const float* __restrict__ w1, const float* __restrict__ b1, const float* __restrict__ s1, const float* __restrict__ t1,
    const float* __restrict__ w2, const float* __restrict__ b2, const float* __restrict__ s2, const float* __restrict__ t2,
    float* __restrict__ out) {
    __shared__ float g0[1024], g1[512], g2[256];
    const int b = blockIdx.x, tid = threadIdx.x;
    for (int f = tid; f < 1024; f += 256) {
        float z = fdec(M[b * 1024 + f]);
        float g = cs[f] * (z + cb[f]) + ct[f];
        g0[f] = fmaxf(g, 0.f);
    }
    __syncthreads();
    for (int f = tid; f < 512; f += 256) {
        const float4* wp = (const float4*)(w0 + (size_t)f * 1024);
        float acc = 0.f;
#pragma unroll 4
        for (int c = 0; c < 256; ++c) {
            float4 wv = wp[c];
            float4 gv = *(const float4*)&g0[c * 4];
            acc += wv.x * gv.x + wv.y * gv.y + wv.z * gv.z + wv.w * gv.w;
        }
        float g = s0[f] * (acc + b0[f]) + t0[f];
        g1[f] = fmaxf(g, 0.f);
    }
    __syncthreads();
    if (tid < 256) {
        const float4* wp = (const float4*)(w1 + (size_t)tid * 512);
        float acc = 0.f;
#pragma unroll 4
        for (int c = 0; c < 128; ++c) {
            float4 wv = wp[c];
            float4 gv = *(const float4*)&g1[c * 4];
            acc += wv.x * gv.x + wv.y * gv.y + wv.z * gv.z + wv.w * gv.w;
        }
        float g = s1[tid] * (acc + b1[tid]) + t1[tid];
        g2[tid] = fmaxf(g, 0.f);
    }
    __syncthreads();
    if (tid < 40) {
        const float4* wp = (const float4*)(w2 + (size_t)tid * 256);
        float acc = 0.f;
#pragma unroll 4
        for (int c = 0; c < 64; ++c) {
            float4 wv = wp[c];
            float4 gv = *(const float4*)&g2[c * 4];
            acc += wv.x * gv.x + wv.y * gv.y + wv.z * gv.z + wv.w * gv.w;
        }
        float g = s2[tid] * (acc + b2[tid]) + t2[tid];
        out[b * 40 + tid] = fmaxf(g, 0.f);
    }
}

// ---------------------------------------------------------------------------
extern "C" void kernel_launch(void* const* d_in, const int* in_sizes, int n_in,
                              void* d_out, int out_size, void* d_ws, size_t ws_size,
                              hipStream_t stream) {
    const float* x       = (const float*)d_in[0];
    const float* ec0_w   = (const float*)d_in[1];
    const float* ec0_b   = (const float*)d_in[2];
    const float* ec1_w   = (const float*)d_in[3];
    const float* ec1_b   = (const float*)d_in[4];
    const float* ec2_w   = (const float*)d_in[5];
    const float* ec2_b   = (const float*)d_in[6];
    const float* ec3_w   = (const float*)d_in[7];
    const float* ec3_b   = (const float*)d_in[8];
    const float* conv0_w = (const float*)d_in[9];
    const float* conv0_b = (const float*)d_in[10];
    const float* conv0_s = (const float*)d_in[11];
    const float* conv0_t = (const float*)d_in[12];
    const float* fc0_w   = (const float*)d_in[13];
    const float* fc0_b   = (const float*)d_in[14];
    const float* fc0_s   = (const float*)d_in[15];
    const float* fc0_t   = (const float*)d_in[16];
    const float* fc1_w   = (const float*)d_in[17];
    const float* fc1_b   = (const float*)d_in[18];
    const float* fc1_s   = (const float*)d_in[19];
    const float* fc1_t   = (const float*)d_in[20];
    const float* fc2_w   = (const float*)d_in[21];
    const float* fc2_b   = (const float*)d_in[22];
    const float* fc2_s   = (const float*)d_in[23];
    const float* fc2_t   = (const float*)d_in[24];
    float* out = (float*)d_out;

    char* ws = (char*)d_ws;
    const int B = 16, N = NPTS;
    float* Hc   = (float*)(ws + 0);            // [16][320][2048]  41,943,040 B
    float* U    = (float*)(ws + 41943040);     // [16][2048][128]  16,777,216 B
    float* T    = (float*)(ws + 58720256);     // [16][128][2048]  16,777,216 B
    int*   I    = (int*)  (ws + 75497472);     // [16][2048][20]    2,621,440 B
    unsigned* M = (unsigned*)(ws + 78118912);  // [16][1024]           65,536 B
    unsigned short* W_hi = (unsigned short*)(ws + 78184448);  //  655,360 B
    unsigned short* W_lo = (unsigned short*)(ws + 78839808);  //  655,360 B
    unsigned short* HtH  = (unsigned short*)(ws + 79495168);  // [16][2048][320] 20,971,520 B
    unsigned short* HtL  = (unsigned short*)(ws + 100466688); // [16][2048][320] 20,971,520 B
    // end: 121,438,208 B

    (void)hipFuncSetAttribute((const void*)knnfused_kernel,
                              hipFuncAttributeMaxDynamicSharedMemorySize, 73728);

    dim3 blk(256);
    const int bsX0 = 3 * N, bsH = 320 * N;

    wsplit_kernel<<<dim3(1024 * 320 / 256), blk, 0, stream>>>(conv0_w, W_hi, W_lo);

    // ---- Layer 0 (C=3 -> F=64) ----
    select0_kernel<<<dim3(B * N / 4), blk, 0, stream>>>(x, I);
    ut_kernel<64, 3><<<dim3(N / 64, 1, B), blk, 0, stream>>>(x, bsX0, ec0_w, ec0_b, U, T);
    gathermax_kernel<64, true><<<dim3(N / 32, B), blk, 0, stream>>>(U, T, I, Hc, bsH, HtH, HtL, 0);

    // ---- Layers 1..3 (C=64): fused dist+select with inline sq ----
    const float* Xin[3] = {Hc, Hc + (size_t)64 * N, Hc + (size_t)128 * N};
    const float* ecw[3] = {ec1_w, ec2_w, ec3_w};
    const float* ecb[3] = {ec1_b, ec2_b, ec3_b};
    for (int L = 0; L < 3; ++L) {
        knnfused_kernel<<<dim3(N / 16, B), dim3(512), 73728, stream>>>(Xin[L], bsH, I);
        if (L < 2) {
            ut_kernel<64, 64><<<dim3(N / 64, 1, B), blk, 0, stream>>>(Xin[L], bsH, ecw[L], ecb[L], U, T);
            gathermax_kernel<64, true><<<dim3(N / 32, B), blk, 0, stream>>>(
                U, T, I, Hc + (size_t)(64 * (L + 1)) * N, bsH, HtH, HtL, 64 * (L + 1));
        } else {
            ut_kernel<128, 64><<<dim3(N / 64, 2, B), blk, 0, stream>>>(Xin[L], bsH, ecw[L], ecb[L], U, T);
            gathermax_kernel<128, false><<<dim3(N / 32, B), blk, 0, stream>>>(
                U, T, I, Hc + (size_t)192 * N, bsH, HtH, HtL, 192);
        }
    }

    // ---- conv0 + global max (bf16x3 MFMA) ----
    (void)hipMemsetAsync(M, 0, B * 1024 * sizeof(unsigned), stream);
    conv0mfma_kernel<<<dim3(N / 64, 1024 / 128, B), blk, 0, stream>>>(HtH, HtL, W_hi, W_lo, M);

    // ---- head ----
    fc_kernel<<<dim3(B), blk, 0, stream>>>(M, conv0_b, conv0_s, conv0_t,
                                           fc0_w, fc0_b, fc0_s, fc0_t,
                                           fc1_w, fc1_b, fc1_s, fc1_t,
                                           fc2_w, fc2_b, fc2_s, fc2_t, out);
}

// Round 6
// 874.774 us; speedup vs baseline: 1.3969x; 1.0873x over previous
//
#include <hip/hip_runtime.h>

#define DEVINL __device__ __forceinline__

static const int NPTS = 2048;

typedef __attribute__((ext_vector_type(8))) short bf16x8;
typedef __attribute__((ext_vector_type(4))) float f32x4;

DEVINL unsigned fenc(float x) {
    int b = __float_as_int(x);
    return (b < 0) ? ~(unsigned)b : ((unsigned)b | 0x80000000u);
}
DEVINL float fdec(unsigned u) {
    return (u & 0x80000000u) ? __int_as_float((int)(u & 0x7fffffffu))
                             : __int_as_float((int)~u);
}
DEVINL unsigned long long u64min(unsigned long long a, unsigned long long b) {
    return (b < a) ? b : a;
}
DEVINL unsigned short f2bf(float x) {  // round-to-nearest-even bf16 (finite inputs)
    unsigned u = __float_as_uint(x);
    return (unsigned short)((u + 0x7fffu + ((u >> 16) & 1u)) >> 16);
}
DEVINL float bf2f(unsigned short h) { return __uint_as_float(((unsigned)h) << 16); }

// ---------------------------------------------------------------------------
// Exact top-20 of a row held as v[32] per lane (col(j) = lane*4+(j&3)+(j>>2)*256).
// tau = 20th smallest of the 64 lane-minima; ballot-compact <=tau (E~25) ->
// u64 bitonic sort -> lanes 0..19. Fallback (>64 cands, ~never): low-register
// 20-round lexicographic (fenc(v), col) tournament with a taken-bitmask.
// ---------------------------------------------------------------------------
DEVINL void topk20(float v[32], unsigned long long* cand, int lane,
                   int* __restrict__ Iout, int outBase) {
    float t16[16];
#pragma unroll
    for (int i = 0; i < 16; ++i) t16[i] = fminf(v[i], v[i + 16]);
#pragma unroll
    for (int i = 0; i < 8; ++i) t16[i] = fminf(t16[i], t16[i + 8]);
#pragma unroll
    for (int i = 0; i < 4; ++i) t16[i] = fminf(t16[i], t16[i + 4]);
    float s = fminf(fminf(t16[0], t16[1]), fminf(t16[2], t16[3]));
#pragma unroll
    for (int k = 2; k <= 64; k <<= 1) {
#pragma unroll
        for (int j = k >> 1; j >= 1; j >>= 1) {
            float o = __shfl_xor(s, j);
            bool keepmin = (((lane & j) == 0) == ((lane & k) == 0));
            s = keepmin ? fminf(s, o) : fmaxf(s, o);
        }
    }
    const float tau = __shfl(s, 19);
    int cnt = 0;
#pragma unroll
    for (int j = 0; j < 32; ++j) {
        bool pass = (v[j] <= tau);
        unsigned long long mask = __ballot(pass);
        if (pass) {
            int pos = cnt + (int)__popcll(mask & ((1ull << lane) - 1ull));
            if (pos < 64) {
                int col = lane * 4 + (j & 3) + ((j >> 2) << 8);
                cand[pos] = ((unsigned long long)fenc(v[j]) << 32) | (unsigned)col;
            }
        }
        cnt += (int)__popcll(mask);
    }
    if (cnt <= 64) {
        unsigned long long key = (lane < cnt) ? cand[lane] : ~0ull;
#pragma unroll
        for (int k = 2; k <= 64; k <<= 1) {
#pragma unroll
            for (int j = k >> 1; j >= 1; j >>= 1) {
                unsigned long long o = __shfl_xor(key, j);
                bool keepmin = (((lane & j) == 0) == ((lane & k) == 0));
                unsigned long long mn = u64min(key, o);
                unsigned long long mx = (key ^ o) ^ mn;
                key = keepmin ? mn : mx;
            }
        }
        if (lane < 20) Iout[outBase + lane] = (int)(unsigned)(key & 0xffffffffu);
    } else {
        // Cold exact path: 20 rounds of global lex-min over (fenc(v), col).
        unsigned vu[32];
#pragma unroll
        for (int j = 0; j < 32; ++j) vu[j] = fenc(v[j]);
        unsigned taken = 0u;
        for (int it = 0; it < 20; ++it) {
            unsigned bk = 0xffffffffu;
            int bc = 0x7fffffff, bj = 0;
#pragma unroll
            for (int j = 0; j < 32; ++j) {
                const int col = lane * 4 + (j & 3) + ((j >> 2) << 8);
                bool avail = ((taken >> j) & 1u) == 0u;
                bool better = avail && (vu[j] < bk || (vu[j] == bk && col < bc));
                bk = better ? vu[j] : bk;
                bc = better ? col : bc;
                bj = better ? j : bj;
            }
            const int lbc = bc;  // lane-local winner col (unique across lanes)
#pragma unroll
            for (int off = 32; off >= 1; off >>= 1) {
                unsigned ok = __shfl_xor(bk, off);
                int oc = __shfl_xor(bc, off);
                bool t = (ok < bk) || (ok == bk && oc < bc);
                bk = t ? ok : bk;
                bc = t ? oc : bc;
            }
            if (lane == 0) Iout[outBase + it] = bc;
            if (lbc == bc) taken |= (1u << bj);
        }
    }
}

// ---------------------------------------------------------------------------
// Fused KNN (C=64), 16 rows/block, B streamed from L2. rd5 PMC: FETCH_SIZE
// 32.9MB vs 8MB ideal = 4x L2 thrash (blocks of one batch scattered over all
// 8 XCDs; 16 panels don't fit a 4MB XCD L2). XCD-aware remap: linear block id
// round-robins XCDs, so map lin%8==k -> batches {2k,2k+1}; per-XCD working
// set 2x512KB=1MB -> panel reads become L2 hits, killing the 27% VALU idle.
// Bijective remap, pure reordering -> bit-identical output.
// ---------------------------------------------------------------------------
__global__ __launch_bounds__(512, 2) void knnfused_kernel(const float* __restrict__ X, int bs,
                                                          int* __restrict__ Iout) {
    extern __shared__ char smem[];
    float* Dr = (float*)smem;                                       // [8][2048] 64 KB
    float* As = (float*)(smem + 65536);                             // [64][16]   4 KB
    unsigned long long* cand = (unsigned long long*)(smem + 69632); // [8][64]    4 KB
    const int N = NPTS, K = 20;
    // XCD-aware remap: grid (128, 16); lin%8 = XCD; 2 batches per XCD.
    const int lin = blockIdx.x + 128 * blockIdx.y;
    const int jj = lin >> 3;
    const int b = (lin & 7) * 2 + (jj >> 7);
    const int n0 = (jj & 127) * 16;
    const float* __restrict__ Xb = X + (size_t)b * bs;
    const int tid = threadIdx.x;
    if (tid < 256) {
        int c = tid >> 2, r4 = (tid & 3) * 4;
        *(float4*)&As[c * 16 + r4] = *(const float4*)&Xb[(size_t)c * N + n0 + r4];
    }
    __syncthreads();
    const int m0 = tid * 4;
    float acc[16][4], sq[4];
#pragma unroll
    for (int r = 0; r < 16; ++r)
#pragma unroll
        for (int j = 0; j < 4; ++j) acc[r][j] = 0.f;
#pragma unroll
    for (int j = 0; j < 4; ++j) sq[j] = 0.f;
#pragma unroll 2
    for (int c = 0; c < 64; ++c) {
        float4 b0 = *(const float4*)&Xb[(size_t)c * N + m0];
        sq[0] += b0.x * b0.x; sq[1] += b0.y * b0.y;
        sq[2] += b0.z * b0.z; sq[3] += b0.w * b0.w;
        {
            float4 a0 = *(const float4*)&As[c * 16];
            float4 a1 = *(const float4*)&As[c * 16 + 4];
            float av[8] = {a0.x, a0.y, a0.z, a0.w, a1.x, a1.y, a1.z, a1.w};
#pragma unroll
            for (int r = 0; r < 8; ++r) {
                acc[r][0] += av[r] * b0.x; acc[r][1] += av[r] * b0.y;
                acc[r][2] += av[r] * b0.z; acc[r][3] += av[r] * b0.w;
            }
        }
        {
            float4 a2 = *(const float4*)&As[c * 16 + 8];
            float4 a3 = *(const float4*)&As[c * 16 + 12];
            float aw[8] = {a2.x, a2.y, a2.z, a2.w, a3.x, a3.y, a3.z, a3.w};
#pragma unroll
            for (int r = 0; r < 8; ++r) {
                acc[8 + r][0] += aw[r] * b0.x; acc[8 + r][1] += aw[r] * b0.y;
                acc[8 + r][2] += aw[r] * b0.z; acc[8 + r][3] += aw[r] * b0.w;
            }
        }
    }
    const float INF = __builtin_inff();
    // ---- rows 0..7: d -> Dr ----
#pragma unroll
    for (int r = 0; r < 8; ++r) {
        const int n = n0 + r;
        float d0[4] = {sq[0] - 2.f * acc[r][0], sq[1] - 2.f * acc[r][1],
                       sq[2] - 2.f * acc[r][2], sq[3] - 2.f * acc[r][3]};
#pragma unroll
        for (int j = 0; j < 4; ++j) {
            if (m0 + j == n) d0[j] = INF;
        }
        *(float4*)&Dr[r * N + m0] = make_float4(d0[0], d0[1], d0[2], d0[3]);
    }
    // ---- rows 8..15: convert acc -> d in registers (sq then dead) ----
    float dd[8][4];
#pragma unroll
    for (int r = 0; r < 8; ++r) {
        const int n = n0 + 8 + r;
#pragma unroll
        for (int j = 0; j < 4; ++j) {
            float d = sq[j] - 2.f * acc[8 + r][j];
            dd[r][j] = (m0 + j == n) ? INF : d;
        }
    }
    __syncthreads();  // Dr rows 0..7 visible
    const int w = tid >> 6, lane = tid & 63;
    const float* __restrict__ rp = &Dr[w * N];
    float v[32];
#pragma unroll
    for (int q = 0; q < 8; ++q) {
        float4 x4 = *(const float4*)&rp[lane * 4 + q * 256];
        v[q * 4 + 0] = x4.x; v[q * 4 + 1] = x4.y;
        v[q * 4 + 2] = x4.z; v[q * 4 + 3] = x4.w;
    }
    __syncthreads();  // pass-1 reads done; Dr reusable
    // ---- write rows 8..15 into Dr (dd dies here, BEFORE topk) ----
#pragma unroll
    for (int r = 0; r < 8; ++r) {
        *(float4*)&Dr[r * N + m0] = make_float4(dd[r][0], dd[r][1], dd[r][2], dd[r][3]);
    }
    topk20(v, cand + w * 64, lane, Iout, (b * N + n0 + w) * K);
    __syncthreads();  // rows 8..15 stores visible
#pragma unroll
    for (int q = 0; q < 8; ++q) {
        float4 x4 = *(const float4*)&rp[lane * 4 + q * 256];
        v[q * 4 + 0] = x4.x; v[q * 4 + 1] = x4.y;
        v[q * 4 + 2] = x4.z; v[q * 4 + 3] = x4.w;
    }
    topk20(v, cand + w * 64, lane, Iout, (b * N + n0 + 8 + w) * K);
}

// ---------------------------------------------------------------------------
// select0: layer-0 (C=3) — scores inline, register topk. (x is 1.5MB total —
// no XCD remap needed.)
// ---------------------------------------------------------------------------
__global__ __launch_bounds__(256) void select0_kernel(const float* __restrict__ X,
                                                      int* __restrict__ Iout) {
    const int N = NPTS, K = 20;
    __shared__ unsigned long long cand[4][64];
    const int w = threadIdx.x >> 6, lane = threadIdx.x & 63;
    const int rowg = blockIdx.x * 4 + w;
    const int b = rowg >> 11, n = rowg & 2047;
    const float* __restrict__ Xb = X + (size_t)b * 3 * N;
    const float xr = Xb[n], yr = Xb[N + n], zr = Xb[2 * N + n];
    const float INF = __builtin_inff();
    float v[32];
#pragma unroll
    for (int q = 0; q < 8; ++q) {
        const int base = lane * 4 + q * 256;
        const float4 xm = *(const float4*)&Xb[base];
        const float4 ym = *(const float4*)&Xb[N + base];
        const float4 zm = *(const float4*)&Xb[2 * N + base];
        float mx[4] = {xm.x, xm.y, xm.z, xm.w};
        float my[4] = {ym.x, ym.y, ym.z, ym.w};
        float mz[4] = {zm.x, zm.y, zm.z, zm.w};
#pragma unroll
        for (int j = 0; j < 4; ++j) {
            float sq = mx[j] * mx[j] + my[j] * my[j] + mz[j] * mz[j];
            float dot = xr * mx[j] + yr * my[j] + zr * mz[j];
            float d = sq - 2.f * dot;
            v[q * 4 + j] = (base + j == n) ? INF : d;
        }
    }
    topk20(v, &cand[w][0], lane, Iout, (b * N + n) * K);
}

// ---------------------------------------------------------------------------
// U/T GEMMs — XCD-aware batch remap (2 batches per XCD, X panel L2-resident).
// ---------------------------------------------------------------------------
template<int F, int C>
__global__ __launch_bounds__(256) void ut_kernel(const float* __restrict__ X, int bs,
                                                 const float* __restrict__ W,
                                                 const float* __restrict__ bias,
                                                 float* __restrict__ U, float* __restrict__ T) {
    const int N = NPTS;
    __shared__ float Ws2[64][C + 1];
    __shared__ float Wsd[64][C + 1];
    constexpr int FB = F / 64;            // f-blocks per batch
    constexpr int PB = 32 * FB;           // blocks per batch
    const int lin = blockIdx.x + 32 * (blockIdx.y + FB * blockIdx.z);
    const int jj = lin >> 3;              // < 2*PB
    const int b = (lin & 7) * 2 + jj / PB;
    const int wb = jj % PB;
    const int n0 = (wb % 32) * 64, f0 = (wb / 32) * 64;
    const int tid = threadIdx.x;
    for (int i = tid; i < 64 * C; i += 256) {
        int ff = i / C, c = i - ff * C;
        float w1 = W[(f0 + ff) * (2 * C) + c];
        float w2 = W[(f0 + ff) * (2 * C) + C + c];
        Ws2[ff][c] = w2;
        Wsd[ff][c] = w1 - w2;
    }
    __syncthreads();
    const int nt = tid & 15, fg = tid >> 4;
    const float* __restrict__ Xb = X + (size_t)b * bs;
    float au[4][4], av[4][4];
#pragma unroll
    for (int i = 0; i < 4; ++i)
#pragma unroll
        for (int j = 0; j < 4; ++j) { au[i][j] = 0.f; av[i][j] = 0.f; }
#pragma unroll 4
    for (int c = 0; c < C; ++c) {
        const float4 xv = *(const float4*)&Xb[(size_t)c * N + n0 + nt * 4];
#pragma unroll
        for (int fi = 0; fi < 4; ++fi) {
            float w2v = Ws2[fg * 4 + fi][c];
            float wdv = Wsd[fg * 4 + fi][c];
            au[fi][0] += w2v * xv.x; au[fi][1] += w2v * xv.y;
            au[fi][2] += w2v * xv.z; au[fi][3] += w2v * xv.w;
            av[fi][0] += wdv * xv.x; av[fi][1] += wdv * xv.y;
            av[fi][2] += wdv * xv.z; av[fi][3] += wdv * xv.w;
        }
    }
#pragma unroll
    for (int ni = 0; ni < 4; ++ni) {
        int n = n0 + nt * 4 + ni;
        float4 uv = make_float4(au[0][ni], au[1][ni], au[2][ni], au[3][ni]);
        *(float4*)&U[((size_t)b * N + n) * F + f0 + fg * 4] = uv;
    }
#pragma unroll
    for (int fi = 0; fi < 4; ++fi) {
        int f = f0 + fg * 4 + fi;
        float bv = bias[f];
        float4 tv = make_float4(av[fi][0] + bv, av[fi][1] + bv, av[fi][2] + bv, av[fi][3] + bv);
        *(float4*)&T[((size_t)b * F + f) * N + n0 + nt * 4] = tv;
    }
}

// ---------------------------------------------------------------------------
// Gather-max — XCD-aware batch remap (U panel per batch 512KB/1MB; gathers
// become L2 hits when each XCD serves only 2 batches).
// ---------------------------------------------------------------------------
template<int F, bool WRITE_F32>
__global__ __launch_bounds__(256) void gathermax_kernel(const float* __restrict__ U,
                                                        const float* __restrict__ T,
                                                        const int* __restrict__ idx,
                                                        float* __restrict__ Y, int bsY,
                                                        unsigned short* __restrict__ HtH,
                                                        unsigned short* __restrict__ HtL,
                                                        int hoff) {
    const int N = NPTS, K = 20, FG = F / 8;
    __shared__ int sidx[32 * 20];
    // grid (64, 16): lin%8 = XCD; 2 batches per XCD.
    const int lin = blockIdx.x + 64 * blockIdx.y;
    const int jj = lin >> 3;              // 0..127
    const int b = (lin & 7) * 2 + (jj >> 6);
    const int n0 = (jj & 63) * 32;
    const int tid = threadIdx.x;
    const int p = tid >> 3, fg = tid & 7;
    for (int t = tid; t < 32 * K; t += 256) sidx[t] = idx[(b * N + n0) * K + t];
    __syncthreads();
    const int n = n0 + p;
    const float* __restrict__ Ub = U + (size_t)b * N * F;
    const int fbase = fg * FG;
    float mx[FG];
#pragma unroll
    for (int i = 0; i < FG; ++i) mx[i] = -__builtin_inff();
#pragma unroll 4
    for (int j = 0; j < K; ++j) {
        const int r = sidx[p * K + j];
        const float4* up = (const float4*)&Ub[(size_t)r * F + fbase];
#pragma unroll
        for (int q = 0; q < FG / 4; ++q) {
            float4 a = up[q];
            mx[q * 4 + 0] = fmaxf(mx[q * 4 + 0], a.x);
            mx[q * 4 + 1] = fmaxf(mx[q * 4 + 1], a.y);
            mx[q * 4 + 2] = fmaxf(mx[q * 4 + 2], a.z);
            mx[q * 4 + 3] = fmaxf(mx[q * 4 + 3], a.w);
        }
    }
    float val[FG];
#pragma unroll
    for (int i = 0; i < FG; ++i) {
        const int f = fbase + i;
        val[i] = T[((size_t)b * F + f) * N + n] + mx[i];
        if (WRITE_F32) Y[(size_t)b * bsY + (size_t)f * N + n] = val[i];
    }
    // bf16 hi/lo split, c-contiguous at Ht[b][n][hoff + fbase ...]
    unsigned short hs[FG], ls[FG];
#pragma unroll
    for (int i = 0; i < FG; ++i) {
        unsigned short h = f2bf(val[i]);
        hs[i] = h;
        ls[i] = f2bf(val[i] - bf2f(h));
    }
    const size_t hb = ((size_t)b * N + n) * 320 + hoff + fbase;
#pragma unroll
    for (int q = 0; q < FG / 8; ++q) {
        *(int4*)&HtH[hb + q * 8] = *(const int4*)&hs[q * 8];
        *(int4*)&HtL[hb + q * 8] = *(const int4*)&ls[q * 8];
    }
}

// ---------------------------------------------------------------------------
// conv0_w -> bf16 hi/lo split (one-shot, 1024x320 elements).
// ---------------------------------------------------------------------------
__global__ __launch_bounds__(256) void wsplit_kernel(const float* __restrict__ W,
                                                     unsigned short* __restrict__ WH,
                                                     unsigned short* __restrict__ WL) {
    const int e = blockIdx.x * 256 + threadIdx.x;
    float w = W[e];
    unsigned short h = f2bf(w);
    WH[e] = h;
    WL[e] = f2bf(w - bf2f(h));
}

// ---------------------------------------------------------------------------
// conv0 + global max via bf16x3 MFMA emulation:
//   W.H ~= Whi.Hhi + Whi.Hlo + Wlo.Hhi  (error ~2^-18 rel per term).
// Block tile: 64 n x 128 f; per wave 32n x 64f = 2x4 16x16x32 tiles, 3 MFMA
// each per 32-c chunk. LDS rows padded to 40 shorts: b128 frag reads spread
// uniformly over all 8 bank-quads (conflict-free).
// ---------------------------------------------------------------------------
__global__ __launch_bounds__(256) void conv0mfma_kernel(const unsigned short* __restrict__ HtH,
                                                        const unsigned short* __restrict__ HtL,
                                                        const unsigned short* __restrict__ WH,
                                                        const unsigned short* __restrict__ WL,
                                                        unsigned* __restrict__ M) {
    const int N = NPTS;
    __shared__ unsigned short HsH[64][40], HsL[64][40], WsH[128][40], WsL[128][40];
    const int n0 = blockIdx.x * 64, f0 = blockIdx.y * 128, b = blockIdx.z;
    const int tid = threadIdx.x;
    const int wave = tid >> 6, lane = tid & 63;
    const int wm = wave & 1, wf = wave >> 1;
    const int row = lane & 15, quad = lane >> 4;
    f32x4 acc[2][4];
#pragma unroll
    for (int i = 0; i < 2; ++i)
#pragma unroll
        for (int j = 0; j < 4; ++j) acc[i][j] = (f32x4){0.f, 0.f, 0.f, 0.f};

    const int hn = tid >> 2, hq = tid & 3;   // H staging: 64 rows x 4 chunks
    const int wfr = tid >> 1, wq = tid & 1;  // W staging: 128 rows x 2 chunks

    for (int c0 = 0; c0 < 320; c0 += 32) {
        {
            const size_t src = ((size_t)b * N + n0 + hn) * 320 + c0 + hq * 8;
            *(int4*)&HsH[hn][hq * 8] = *(const int4*)&HtH[src];
            *(int4*)&HsL[hn][hq * 8] = *(const int4*)&HtL[src];
        }
        {
            const size_t src = (size_t)(f0 + wfr) * 320 + c0 + wq * 16;
            *(int4*)&WsH[wfr][wq * 16]     = *(const int4*)&WH[src];
            *(int4*)&WsH[wfr][wq * 16 + 8] = *(const int4*)&WH[src + 8];
            *(int4*)&WsL[wfr][wq * 16]     = *(const int4*)&WL[src];
            *(int4*)&WsL[wfr][wq * 16 + 8] = *(const int4*)&WL[src + 8];
        }
        __syncthreads();
        bf16x8 aH[2], aL[2];
#pragma unroll
        for (int mt = 0; mt < 2; ++mt) {
            aH[mt] = *(const bf16x8*)&HsH[wm * 32 + mt * 16 + row][quad * 8];
            aL[mt] = *(const bf16x8*)&HsL[wm * 32 + mt * 16 + row][quad * 8];
        }
#pragma unroll
        for (int nt = 0; nt < 4; ++nt) {
            bf16x8 bH = *(const bf16x8*)&WsH[wf * 64 + nt * 16 + row][quad * 8];
            bf16x8 bL = *(const bf16x8*)&WsL[wf * 64 + nt * 16 + row][quad * 8];
#pragma unroll
            for (int mt = 0; mt < 2; ++mt) {
                acc[mt][nt] = __builtin_amdgcn_mfma_f32_16x16x32_bf16(aH[mt], bH, acc[mt][nt], 0, 0, 0);
                acc[mt][nt] = __builtin_amdgcn_mfma_f32_16x16x32_bf16(aH[mt], bL, acc[mt][nt], 0, 0, 0);
                acc[mt][nt] = __builtin_amdgcn_mfma_f32_16x16x32_bf16(aL[mt], bH, acc[mt][nt], 0, 0, 0);
            }
        }
        __syncthreads();
    }
    // D[m=n_pt][col=f]: col = lane&15, row = quad*4 + reg. Max over this
    // wave's 32 n: lane-local (2 mt x 4 regs), then across quads (shfl 16,32).
#pragma unroll
    for (int nt = 0; nt < 4; ++nt) {
        float m = acc[0][nt][0];
#pragma unroll
        for (int r = 1; r < 4; ++r) m = fmaxf(m, acc[0][nt][r]);
#pragma unroll
        for (int r = 0; r < 4; ++r) m = fmaxf(m, acc[1][nt][r]);
        m = fmaxf(m, __shfl_down(m, 16));
        m = fmaxf(m, __shfl_down(m, 32));
        if (quad == 0)
            atomicMax(&M[(b << 10) + f0 + wf * 64 + nt * 16 + row], fenc(m));
    }
}

// ---------------------------------------------------------------------------
// Fused head (unchanged).
// ---------------------------------------------------------------------------
__global__ __launch_bounds__(256) void fc_kernel(const unsigned* __restrict__ M,
    const float* __restrict__ cb, const float* __restrict__ cs, const float* __restrict__ ct,
    const float* __restrict__ w0, const float* __restrict__ b0, const float* __restrict__ s0, const float* __restrict__ t0,
    const float* __restrict__ w1, const float* __restrict__ b1, const float* __restrict__ s1, const float* __restrict__ t1,
    const float* __restrict__ w2, const float* __restrict__ b2, const float* __restrict__ s2, const float* __restrict__ t2,
    float* __restrict__ out) {
    __shared__ float g0[1024], g1[512], g2[256];
    const int b = blockIdx.x, tid = threadIdx.x;
    for (int f = tid; f < 1024; f += 256) {
        float z = fdec(M[b * 1024 + f]);
        float g = cs[f] * (z + cb[f]) + ct[f];
        g0[f] = fmaxf(g, 0.f);
    }
    __syncthreads();
    for (int f = tid; f < 512; f += 256) {
        const float4* wp = (const float4*)(w0 + (size_t)f * 1024);
        float acc = 0.f;
#pragma unroll 4
        for (int c = 0; c < 256; ++c) {
            float4 wv = wp[c];
            float4 gv = *(const float4*)&g0[c * 4];
            acc += wv.x * gv.x + wv.y * gv.y + wv.z * gv.z + wv.w * gv.w;
        }
        float g = s0[f] * (acc + b0[f]) + t0[f];
        g1[f] = fmaxf(g, 0.f);
    }
    __syncthreads();
    if (tid < 256) {
        const float4* wp = (const float4*)(w1 + (size_t)tid * 512);
        float acc = 0.f;
#pragma unroll 4
        for (int c = 0; c < 128; ++c) {
            float4 wv = wp[c];
            float4 gv = *(const float4*)&g1[c * 4];
            acc += wv.x * gv.x + wv.y * gv.y + wv.z * gv.z + wv.w * gv.w;
        }
        float g = s1[tid] * (acc + b1[tid]) + t1[tid];
        g2[tid] = fmaxf(g, 0.f);
    }
    __syncthreads();
    if (tid < 40) {
        const float4* wp = (const float4*)(w2 + (size_t)tid * 256);
        float acc = 0.f;
#pragma unroll 4
        for (int c = 0; c < 64; ++c) {
            float4 wv = wp[c];
            float4 gv = *(const float4*)&g2[c * 4];
            acc += wv.x * gv.x + wv.y * gv.y + wv.z * gv.z + wv.w * gv.w;
        }
        float g = s2[tid] * (acc + b2[tid]) + t2[tid];
        out[b * 40 + tid] = fmaxf(g, 0.f);
    }
}

// ---------------------------------------------------------------------------
extern "C" void kernel_launch(void* const* d_in, const int* in_sizes, int n_in,
                              void* d_out, int out_size, void* d_ws, size_t ws_size,
                              hipStream_t stream) {
    const float* x       = (const float*)d_in[0];
    const float* ec0_w   = (const float*)d_in[1];
    const float* ec0_b   = (const float*)d_in[2];
    const float* ec1_w   = (const float*)d_in[3];
    const float* ec1_b   = (const float*)d_in[4];
    const float* ec2_w   = (const float*)d_in[5];
    const float* ec2_b   = (const float*)d_in[6];
    const float* ec3_w   = (const float*)d_in[7];
    const float* ec3_b   = (const float*)d_in[8];
    const float* conv0_w = (const float*)d_in[9];
    const float* conv0_b = (const float*)d_in[10];
    const float* conv0_s = (const float*)d_in[11];
    const float* conv0_t = (const float*)d_in[12];
    const float* fc0_w   = (const float*)d_in[13];
    const float* fc0_b   = (const float*)d_in[14];
    const float* fc0_s   = (const float*)d_in[15];
    const float* fc0_t   = (const float*)d_in[16];
    const float* fc1_w   = (const float*)d_in[17];
    const float* fc1_b   = (const float*)d_in[18];
    const float* fc1_s   = (const float*)d_in[19];
    const float* fc1_t   = (const float*)d_in[20];
    const float* fc2_w   = (const float*)d_in[21];
    const float* fc2_b   = (const float*)d_in[22];
    const float* fc2_s   = (const float*)d_in[23];
    const float* fc2_t   = (const float*)d_in[24];
    float* out = (float*)d_out;

    char* ws = (char*)d_ws;
    const int B = 16, N = NPTS;
    float* Hc   = (float*)(ws + 0);            // [16][320][2048]  41,943,040 B
    float* U    = (float*)(ws + 41943040);     // [16][2048][128]  16,777,216 B
    float* T    = (float*)(ws + 58720256);     // [16][128][2048]  16,777,216 B
    int*   I    = (int*)  (ws + 75497472);     // [16][2048][20]    2,621,440 B
    unsigned* M = (unsigned*)(ws + 78118912);  // [16][1024]           65,536 B
    unsigned short* W_hi = (unsigned short*)(ws + 78184448);  //  655,360 B
    unsigned short* W_lo = (unsigned short*)(ws + 78839808);  //  655,360 B
    unsigned short* HtH  = (unsigned short*)(ws + 79495168);  // [16][2048][320] 20,971,520 B
    unsigned short* HtL  = (unsigned short*)(ws + 100466688); // [16][2048][320] 20,971,520 B
    // end: 121,438,208 B

    (void)hipFuncSetAttribute((const void*)knnfused_kernel,
                              hipFuncAttributeMaxDynamicSharedMemorySize, 73728);

    dim3 blk(256);
    const int bsX0 = 3 * N, bsH = 320 * N;

    wsplit_kernel<<<dim3(1024 * 320 / 256), blk, 0, stream>>>(conv0_w, W_hi, W_lo);

    // ---- Layer 0 (C=3 -> F=64) ----
    select0_kernel<<<dim3(B * N / 4), blk, 0, stream>>>(x, I);
    ut_kernel<64, 3><<<dim3(N / 64, 1, B), blk, 0, stream>>>(x, bsX0, ec0_w, ec0_b, U, T);
    gathermax_kernel<64, true><<<dim3(N / 32, B), blk, 0, stream>>>(U, T, I, Hc, bsH, HtH, HtL, 0);

    // ---- Layers 1..3 (C=64): fused dist+select with inline sq ----
    const float* Xin[3] = {Hc, Hc + (size_t)64 * N, Hc + (size_t)128 * N};
    const float* ecw[3] = {ec1_w, ec2_w, ec3_w};
    const float* ecb[3] = {ec1_b, ec2_b, ec3_b};
    for (int L = 0; L < 3; ++L) {
        knnfused_kernel<<<dim3(N / 16, B), dim3(512), 73728, stream>>>(Xin[L], bsH, I);
        if (L < 2) {
            ut_kernel<64, 64><<<dim3(N / 64, 1, B), blk, 0, stream>>>(Xin[L], bsH, ecw[L], ecb[L], U, T);
            gathermax_kernel<64, true><<<dim3(N / 32, B), blk, 0, stream>>>(
                U, T, I, Hc + (size_t)(64 * (L + 1)) * N, bsH, HtH, HtL, 64 * (L + 1));
        } else {
            ut_kernel<128, 64><<<dim3(N / 64, 2, B), blk, 0, stream>>>(Xin[L], bsH, ecw[L], ecb[L], U, T);
            gathermax_kernel<128, false><<<dim3(N / 32, B), blk, 0, stream>>>(
                U, T, I, Hc + (size_t)192 * N, bsH, HtH, HtL, 192);
        }
    }

    // ---- conv0 + global max (bf16x3 MFMA) ----
    (void)hipMemsetAsync(M, 0, B * 1024 * sizeof(unsigned), stream);
    conv0mfma_kernel<<<dim3(N / 64, 1024 / 128, B), blk, 0, stream>>>(HtH, HtL, W_hi, W_lo, M);

    // ---- head ----
    fc_kernel<<<dim3(B), blk, 0, stream>>>(M, conv0_b, conv0_s, conv0_t,
                                           fc0_w, fc0_b, fc0_s, fc0_t,
                                           fc1_w, fc1_b, fc1_s, fc1_t,
                                           fc2_w, fc2_b, fc2_s, fc2_t, out);
}